// Round 4
// baseline (849.378 us; speedup 1.0000x reference)
//
#include <hip/hip_runtime.h>
#include <hip/hip_bf16.h>
#include <math.h>

typedef unsigned short u16;
typedef short short8 __attribute__((ext_vector_type(8)));
typedef float floatx4 __attribute__((ext_vector_type(4)));

#define B_    32
#define C_    384
#define N_    3136
#define K_TOP 98
#define NTOK  99
#define TOKS  (B_ * NTOK)   // 3168
#define HEADS_ 8
#define HD    48
#define KDIM  384

__device__ __forceinline__ float b2f(u16 u) {
    unsigned int x = ((unsigned int)u) << 16;
    return __builtin_bit_cast(float, x);
}
__device__ __forceinline__ u16 f2b(float f) {
    unsigned int x = __builtin_bit_cast(unsigned int, f);
    unsigned int r = (x + 0x7fffu + ((x >> 16) & 1u)) >> 16;
    return (u16)r;
}

// ---------------- small prep kernels ----------------

__global__ void k_zero(float* sumsq) { sumsq[threadIdx.x] = 0.f; }

__global__ void k_cvt(const float* __restrict__ src, u16* __restrict__ dst, int n) {
    int i = blockIdx.x * 256 + threadIdx.x;
    if (i < n) dst[i] = f2b(src[i]);
}

// Fused single pass over x: per-(b,c) sums (ch_sum, sumsq), per-p score partials
// over a 64-channel tile, and bf16 copy of x. grid (B_, 6), 256 threads.
__launch_bounds__(256)
__global__ void k_xprep(const float* __restrict__ x, float* __restrict__ ch_sum,
                        float* __restrict__ sumsq, float* __restrict__ spart,
                        u16* __restrict__ xb) {
    int b = blockIdx.x, cg = blockIdx.y;
    int c0 = cg * 64;
    int tid = threadIdx.x;
    int lane = tid & 63;
    int wave = tid >> 6;
    __shared__ float wsum1[64 * 4], wsum2[64 * 4];

    float ps[13];
#pragma unroll
    for (int i = 0; i < 13; ++i) ps[i] = 0.f;

    for (int c = 0; c < 64; ++c) {
        const float* row = x + ((size_t)(b * C_ + c0 + c)) * N_;
        u16* xrow = xb + ((size_t)(b * C_ + c0 + c)) * N_;
        float s1 = 0.f, s2 = 0.f;
#pragma unroll
        for (int i = 0; i < 13; ++i) {
            int p = tid + i * 256;
            if (p < N_) {
                float v = row[p];
                xrow[p] = f2b(v);
                float v2 = v * v;
                s1 += v; s2 += v2; ps[i] += v2;
            }
        }
#pragma unroll
        for (int off = 32; off; off >>= 1) {
            s1 += __shfl_down(s1, off);
            s2 += __shfl_down(s2, off);
        }
        if (lane == 0) { wsum1[c * 4 + wave] = s1; wsum2[c * 4 + wave] = s2; }
    }
    float* sp = spart + (size_t)(b * 6 + cg) * N_;
#pragma unroll
    for (int i = 0; i < 13; ++i) {
        int p = tid + i * 256;
        if (p < N_) sp[p] = ps[i];
    }
    __syncthreads();
    if (tid < 64) {
        int c = tid;
        float a = wsum1[c * 4] + wsum1[c * 4 + 1] + wsum1[c * 4 + 2] + wsum1[c * 4 + 3];
        float q = wsum2[c * 4] + wsum2[c * 4 + 1] + wsum2[c * 4 + 2] + wsum2[c * 4 + 3];
        ch_sum[b * C_ + c0 + c] = a;
        atomicAdd(&sumsq[c0 + c], q);
    }
}

__global__ void k_scores_fin(const float* __restrict__ spart, float* __restrict__ scores) {
    int gid = blockIdx.x * 256 + threadIdx.x;   // B_*N_ threads
    int b = gid / N_;
    int p = gid - b * N_;
    const float* sp = spart + (size_t)b * 6 * N_ + p;
    float s = 0.f;
#pragma unroll
    for (int j = 0; j < 6; ++j) s += sp[(size_t)j * N_];
    scores[gid] = s;
}

// per-batch exact top-98 via 3-pass radix select (ties -> lowest index).
// 1024 threads; single-wave shuffle suffix-scan to find the boundary bin;
// parallel tie collection (serial fallback only if >128 exact ties).
__launch_bounds__(1024)
__global__ void k_topk(const float* __restrict__ scores, int* __restrict__ idx,
                       int* __restrict__ istop) {
    int b = blockIdx.x;
    int tid = threadIdx.x;
    __shared__ unsigned int keys[N_];
    __shared__ int hist[4096];
    __shared__ unsigned int sh_prefix;
    __shared__ int sh_g;
    __shared__ int c1, tc;
    __shared__ int idxbuf[K_TOP];
    __shared__ int tiebuf[128];

    for (int p = tid; p < N_; p += 1024) {
        keys[p] = __builtin_bit_cast(unsigned int, scores[b * N_ + p]);
        istop[b * N_ + p] = 0;
    }

    int Kcur = K_TOP;
    unsigned int prefix = 0;
    int m = 0;
#pragma unroll
    for (int pass = 0; pass < 3; ++pass) {
        const int shift = (pass == 0) ? 20 : (pass == 1 ? 8 : 0);
        const int nbins = (pass == 2) ? 256 : 4096;
        const unsigned int pm = (pass == 0) ? 0u : (pass == 1 ? 0xFFF00000u : 0xFFFFFF00u);
        for (int i = tid; i < nbins; i += 1024) hist[i] = 0;
        __syncthreads();
        for (int p = tid; p < N_; p += 1024) {
            unsigned int u = keys[p];
            if ((u & pm) == prefix) atomicAdd(&hist[(u >> shift) & (nbins - 1)], 1);
        }
        __syncthreads();
        if (tid < 64) {
            int lane = tid;
            int nch = nbins >> 6;           // 64 (passes 0,1) or 4 (pass 2)
            int s = 0;
            for (int j = 0; j < nch; ++j) s += hist[lane * nch + j];
            int suf = s;                    // inclusive suffix sum over lanes >= lane
#pragma unroll
            for (int off = 1; off < 64; off <<= 1) {
                int v = __shfl_down(suf, off);
                if (lane + off < 64) suf += v;
            }
            int above = suf - s;            // sum over lanes > lane
            if (suf >= Kcur && above < Kcur) {   // exactly one lane hits
                int acc = above;
                int bin = (lane + 1) * nch - 1;
                for (;; --bin) {
                    int h = hist[bin];
                    if (acc + h >= Kcur) break;
                    acc += h;
                }
                sh_prefix = prefix | ((unsigned int)bin << shift);
                sh_g = acc;
            }
        }
        __syncthreads();
        prefix = sh_prefix;
        m += sh_g;
        Kcur -= sh_g;
    }

    unsigned int lo = prefix;    // exact K-th largest key
    if (tid == 0) { c1 = 0; tc = 0; }
    __syncthreads();
    for (int p = tid; p < N_; p += 1024) {
        unsigned int u = keys[p];
        if (u > lo) { int pos = atomicAdd(&c1, 1); idxbuf[pos] = p; }
        else if (u == lo) { int pos = atomicAdd(&tc, 1); if (pos < 128) tiebuf[pos] = p; }
    }
    __syncthreads();
    if (tid == 0) {              // ties: the (K-m) lowest indices among keys == lo
        int need = K_TOP - m;
        if (tc <= 128) {
            int cnt = tc;
            for (int r = 0; r < need; ++r) {
                int mi = r;
                for (int q = r + 1; q < cnt; ++q) if (tiebuf[q] < tiebuf[mi]) mi = q;
                int t = tiebuf[mi]; tiebuf[mi] = tiebuf[r]; tiebuf[r] = t;
                idxbuf[m + r] = t;
            }
        } else {                 // degenerate mass-tie fallback (never in practice)
            int picked = 0;
            for (int p = 0; p < N_ && picked < need; ++p)
                if (keys[p] == lo) { idxbuf[m + picked] = p; ++picked; }
        }
    }
    __syncthreads();
    if (tid < K_TOP) {
        int ib = idxbuf[tid];
        idx[b * K_TOP + tid] = ib;
        istop[b * N_ + ib] = tid + 1;
    }
}

// tokensT[c][b*99+j] : gather top tokens + bg token. grid (B_, 6); 4 lanes per c.
__launch_bounds__(256)
__global__ void k_tokens(const float* __restrict__ x, const int* __restrict__ idx,
                         const float* __restrict__ ch_sum, u16* __restrict__ tokensT) {
    int b = blockIdx.x, cg = blockIdx.y;
    __shared__ int il[K_TOP];
    int tid = threadIdx.x;
    if (tid < K_TOP) il[tid] = idx[b * K_TOP + tid];
    __syncthreads();
    int cl = tid >> 2;          // 0..63
    int js = tid & 3;           // 0..3
    int c = cg * 64 + cl;
    const float* xp = x + (size_t)b * C_ * N_ + (size_t)c * N_;
    u16* tp = tokensT + (size_t)c * TOKS + b * NTOK;
    float s = 0.f;
    for (int j = js; j < K_TOP; j += 4) {
        float v = xp[il[j]];
        tp[j] = f2b(v);
        s += v;
    }
    s += __shfl_down(s, 2);
    s += __shfl_down(s, 1);
    if (js == 0) {
        float bg = (ch_sum[b * C_ + c] - s) * (1.0f / (float)(N_ - K_TOP));
        tp[K_TOP] = f2b(bg);
    }
}

__global__ void k_bnfin(const float* ch_sum, const float* sumsq, const float* bn_g,
                        const float* bn_b, float* a_scale, float* b_shift) {
    int c = threadIdx.x;
    float s = 0.f;
    for (int b = 0; b < B_; ++b) s += ch_sum[b * C_ + c];
    float inv_n = 1.0f / (float)(B_ * N_);
    float mu = s * inv_n;
    float var = sumsq[c] * inv_n - mu * mu;
    float a = rsqrtf(var + 1e-5f) * bn_g[c];
    a_scale[c] = a;
    b_shift[c] = bn_b[c] - mu * a;
}

// grid 96: wave per output c; coalesced row reads + shuffle reduce
__global__ void k_bias2p(const float* __restrict__ fc2_w, const float* __restrict__ fc2_b,
                         const float* __restrict__ dw_b, float* __restrict__ bias2p) {
    int c = blockIdx.x * 4 + (threadIdx.x >> 6);
    int l = threadIdx.x & 63;
    float acc = 0.f;
    for (int k = l; k < C_; k += 64) acc += fc2_w[c * C_ + k] * dw_b[k];
#pragma unroll
    for (int off = 32; off; off >>= 1) acc += __shfl_down(acc, off);
    if (l == 0) bias2p[c] = acc + fc2_b[c];
}

__global__ void k_biasM(const float* __restrict__ proj_w, const float* __restrict__ proj_b,
                        const float* __restrict__ bias2p, float* __restrict__ biasM) {
    int o = blockIdx.x * 4 + (threadIdx.x >> 6);
    int l = threadIdx.x & 63;
    float acc = 0.f;
    for (int c = l; c < C_; c += 64) acc += proj_w[o * C_ + c] * bias2p[c];
#pragma unroll
    for (int off = 32; off; off >>= 1) acc += __shfl_down(acc, off);
    if (l == 0) biasM[o] = acc + proj_b[o];
}

__global__ void k_bias1(const float* __restrict__ fc1_w, const float* __restrict__ fc1_b,
                        const float* __restrict__ b_shift, float* __restrict__ bias1) {
    int o = blockIdx.x * 4 + (threadIdx.x >> 6);
    int l = threadIdx.x & 63;
    float acc = 0.f;
    for (int c = l; c < C_; c += 64) acc += fc1_w[o * C_ + c] * b_shift[c];
#pragma unroll
    for (int off = 32; off; off >>= 1) acc += __shfl_down(acc, off);
    if (l == 0) bias1[o] = acc + fc1_b[o];
}

// grid (96, B_): wave per (b,o)
__global__ void k_cbias(const float* __restrict__ proj_w, const float* __restrict__ biasM,
                        const float* __restrict__ bgres, float* __restrict__ cbias) {
    int b = blockIdx.y;
    int o = blockIdx.x * 4 + (threadIdx.x >> 6);
    int l = threadIdx.x & 63;
    float acc = 0.f;
    for (int c = l; c < C_; c += 64) acc += proj_w[o * C_ + c] * bgres[b * C_ + c];
#pragma unroll
    for (int off = 32; off; off >>= 1) acc += __shfl_down(acc, off);
    if (l == 0) cbias[b * C_ + o] = acc + biasM[o];
}

// Mw[o][c] = sum_k proj[o][k]*fc2[k][c]  (f32 -> bf16)
__global__ void k_mw(const float* __restrict__ proj_w, const float* __restrict__ fc2_w,
                     u16* __restrict__ Mw) {
    int o = blockIdx.x, c = threadIdx.x;
    float acc = 0.f;
    for (int k = 0; k < C_; ++k) acc += proj_w[o * C_ + k] * fc2_w[k * C_ + c];
    Mw[o * C_ + c] = f2b(acc);
}

__global__ void k_w1p(const float* fc1_w, const float* a_scale, u16* W1p) {
    int i = blockIdx.x * 256 + threadIdx.x;
    if (i < C_ * C_) {
        int c = i % C_;
        W1p[i] = f2b(fc1_w[i] * a_scale[c]);
    }
}

// ---------------- qkv GEMM (M=1152, NC=3168): bf16 MFMA, f32 out ----------------
__launch_bounds__(256)
__global__ void k_gemm_qkv(const u16* __restrict__ A, const u16* __restrict__ Bsrc,
                           const float* __restrict__ biasB, float* __restrict__ outF) {
    const int ldB = TOKS, NC = TOKS;
    int m0 = blockIdx.x * 128;
    int n0 = blockIdx.y * 64;
    int tid = threadIdx.x;
    int lane = tid & 63;
    int wave = tid >> 6;
    int wm0 = (wave >> 1) * 64;
    int wn0 = (wave & 1) * 32;
    int lm = lane & 15;
    int quad = lane >> 4;

    __shared__ __attribute__((aligned(16))) u16 Al[128 * 32];
    __shared__ __attribute__((aligned(16))) u16 Bl[64 * 32];

    floatx4 acc[4][2];
#pragma unroll
    for (int i = 0; i < 4; ++i)
#pragma unroll
        for (int j = 0; j < 2; ++j)
#pragma unroll
            for (int r = 0; r < 4; ++r) acc[i][j][r] = 0.f;

    int ar = tid >> 2;
    int akc = (tid & 3) * 8;
    int bp = tid & 63;
    int bgi = tid >> 6;
    int bswz = ((bgi ^ ((bp >> 1) & 3)) & 3) * 8;
    int bcol = n0 + bp;
    bool bok = bcol < NC;

    for (int kt = 0; kt < 12; ++kt) {
        int k0 = kt * 32;
        __syncthreads();
#pragma unroll
        for (int i = 0; i < 2; ++i) {
            int r = ar + i * 64;
            short8 v = *(const short8*)(const void*)(A + (size_t)(m0 + r) * KDIM + k0 + akc);
            *(short8*)(void*)&Al[r * 32 + akc] = v;
        }
        {
            const u16* src = Bsrc + (size_t)(k0 + bgi * 8) * ldB + bcol;
            short8 v;
#pragma unroll
            for (int j = 0; j < 8; ++j)
                v[j] = bok ? (short)src[(size_t)j * ldB] : (short)0;
            *(short8*)(void*)&Bl[bp * 32 + bswz] = v;
        }
        __syncthreads();
        short8 af[4], bfv[2];
#pragma unroll
        for (int mt = 0; mt < 4; ++mt)
            af[mt] = *(const short8*)(const void*)&Al[(wm0 + mt * 16 + lm) * 32 + quad * 8];
#pragma unroll
        for (int nt = 0; nt < 2; ++nt) {
            int prow = wn0 + nt * 16 + lm;
            int sw = ((quad ^ ((prow >> 1) & 3)) & 3) * 8;
            bfv[nt] = *(const short8*)(const void*)&Bl[prow * 32 + sw];
        }
#pragma unroll
        for (int mt = 0; mt < 4; ++mt)
#pragma unroll
            for (int nt = 0; nt < 2; ++nt)
                acc[mt][nt] = __builtin_amdgcn_mfma_f32_16x16x32_bf16(af[mt], bfv[nt], acc[mt][nt], 0, 0, 0);
    }

#pragma unroll
    for (int nt = 0; nt < 2; ++nt) {
        int col = n0 + wn0 + nt * 16 + lm;
        if (col >= NC) continue;
#pragma unroll
        for (int mt = 0; mt < 4; ++mt)
#pragma unroll
            for (int r = 0; r < 4; ++r) {
                int o = m0 + wm0 + mt * 16 + quad * 4 + r;
                outF[(size_t)o * TOKS + col] = acc[mt][nt][r] + biasB[o];
            }
    }
}

// ---------------- tall GEMM: OUT[0..383][n0..n0+63] = A(384x384,bf16) * B(u16) ----------------
// 8 waves x 48 rows, K chunked 3x128, double-buffered LDS, T14 async-stage split.
// Conflict-free XOR layout: LDS [col][128] u16, u16idx = col*128 + ((win ^ (col&7))*8) + (k&7),
// win = k>>3. Both write (short8/thread) and read (b128 fragments) have every 8-lane
// phase covering all 32 banks.
template<int MODE>
__launch_bounds__(512, 4)
__global__ void k_gemm2(const u16* __restrict__ A, const u16* __restrict__ B0, long bStride,
                        const float* __restrict__ biasF,
                        float* __restrict__ outF,
                        u16* __restrict__ outB,
                        const float* __restrict__ cbias, const int* __restrict__ istop,
                        const float* __restrict__ delta2) {
    const int ldB = N_;
    int b = blockIdx.y;
    int n0 = blockIdx.x * 64;
    const u16* Bsrc = B0 + (size_t)b * bStride;
    int tid = threadIdx.x;
    int lane = tid & 63;
    int wave = tid >> 6;          // 0..7
    int wm0 = wave * 48;
    int lm = lane & 15;
    int quad = lane >> 4;

    __shared__ __attribute__((aligned(16))) u16 Bl[2][64 * 128];   // 32 KB

    // staging role: col sc (0..63), k-group kg (0..7); two short8 per chunk
    int sc = tid & 63;
    int kg = tid >> 6;
    int w0 = ((kg ^ (sc & 7)) * 8);     // u16 offset of first window within col row
    const u16* bsp = Bsrc + (size_t)n0 + sc;

    floatx4 acc[3][4];
#pragma unroll
    for (int i = 0; i < 3; ++i)
#pragma unroll
        for (int j = 0; j < 4; ++j)
#pragma unroll
            for (int r = 0; r < 4; ++r) acc[i][j][r] = 0.f;

    short8 r0, r1;
    // prologue: load + store chunk 0 into buf 0
    {
        const u16* p0 = bsp + (size_t)(kg * 8) * ldB;
        const u16* p1 = bsp + (size_t)(64 + kg * 8) * ldB;
#pragma unroll
        for (int j = 0; j < 8; ++j) { r0[j] = (short)p0[(size_t)j * ldB]; r1[j] = (short)p1[(size_t)j * ldB]; }
        *(short8*)(void*)&Bl[0][sc * 128 + w0] = r0;
        *(short8*)(void*)&Bl[0][sc * 128 + 64 + w0] = r1;
    }
    __syncthreads();

    for (int ch = 0; ch < 3; ++ch) {
        int cur = ch & 1;
        if (ch < 2) {   // issue next chunk's loads early (hide HBM under MFMA)
            const u16* p0 = bsp + (size_t)((ch + 1) * 128 + kg * 8) * ldB;
            const u16* p1 = bsp + (size_t)((ch + 1) * 128 + 64 + kg * 8) * ldB;
#pragma unroll
            for (int j = 0; j < 8; ++j) { r0[j] = (short)p0[(size_t)j * ldB]; r1[j] = (short)p1[(size_t)j * ldB]; }
        }
#pragma unroll
        for (int kt = 0; kt < 4; ++kt) {
            int k0 = ch * 128 + kt * 32;
            short8 af[3], bfv[4];
#pragma unroll
            for (int mt = 0; mt < 3; ++mt)
                af[mt] = *(const short8*)(const void*)(A + (size_t)(wm0 + mt * 16 + lm) * KDIM + k0 + quad * 8);
#pragma unroll
            for (int nt = 0; nt < 4; ++nt) {
                int pc = nt * 16 + lm;
                int win = kt * 4 + quad;
                bfv[nt] = *(const short8*)(const void*)&Bl[cur][pc * 128 + ((win ^ (pc & 7)) * 8)];
            }
#pragma unroll
            for (int mt = 0; mt < 3; ++mt)
#pragma unroll
                for (int nt = 0; nt < 4; ++nt)
                    acc[mt][nt] = __builtin_amdgcn_mfma_f32_16x16x32_bf16(af[mt], bfv[nt], acc[mt][nt], 0, 0, 0);
        }
        if (ch < 2) {   // write staged regs into the other buffer
            *(short8*)(void*)&Bl[cur ^ 1][sc * 128 + w0] = r0;
            *(short8*)(void*)&Bl[cur ^ 1][sc * 128 + 64 + w0] = r1;
            __syncthreads();
        }
    }

#pragma unroll
    for (int nt = 0; nt < 4; ++nt) {
        int ocol = n0 + nt * 16 + lm;
        int tt = 0;
        if (MODE == 3) tt = istop[b * N_ + ocol];
#pragma unroll
        for (int mt = 0; mt < 3; ++mt) {
#pragma unroll
            for (int r = 0; r < 4; ++r) {
                int o = wm0 + mt * 16 + quad * 4 + r;
                float val = acc[mt][nt][r];
                if (MODE == 2) {
                    outF[(size_t)o * N_ + ocol] = val;
                } else if (MODE == 1) {
                    val += biasF[o];
                    float g = 0.5f * val * (1.0f + erff(val * 0.70710678118654752f));
                    outB[(size_t)b * C_ * N_ + (size_t)o * N_ + ocol] = f2b(g);
                } else {
                    val += cbias[b * C_ + o];
                    if (tt) val += delta2[(size_t)o * N_ + b * K_TOP + (tt - 1)];
                    outF[(size_t)b * C_ * N_ + (size_t)o * N_ + ocol] = val;
                }
            }
        }
    }
}

// ---------------- attention (tiny, f32) ----------------

__global__ void k_attn_scores(const float* __restrict__ qkv, float* __restrict__ Sws) {
    int b = blockIdx.x, h = blockIdx.y;
    __shared__ float ql[NTOK * HD], kl[NTOK * HD];
    int tid = threadIdx.x;
    const float scale = 0.14433756729740643f;   // 48^-0.5
    for (int u = tid; u < NTOK * HD; u += 256) {
        int d = u / NTOK, j = u - d * NTOK;
        size_t base = (size_t)(h * HD + d) * TOKS + b * NTOK + j;
        ql[j * HD + d] = qkv[base] * scale;
        kl[j * HD + d] = qkv[base + (size_t)C_ * TOKS];
    }
    __syncthreads();
    float* Sp = Sws + (size_t)(b * HEADS_ + h) * (NTOK * NTOK);
    for (int u = tid; u < NTOK * NTOK; u += 256) {
        int i = u / NTOK, j = u - i * NTOK;
        float s = 0.f;
#pragma unroll 8
        for (int d = 0; d < HD; ++d) s += ql[i * HD + d] * kl[j * HD + d];
        Sp[u] = s;
    }
}

__global__ void k_attn_out(const float* __restrict__ qkv, const float* __restrict__ Sws,
                           u16* __restrict__ diffT, float* __restrict__ bgres) {
    int b = blockIdx.x, h = blockIdx.y;
    __shared__ float vl[NTOK * HD];
    __shared__ float P[NTOK * 100];
    __shared__ float bgrow[HD];
    int tid = threadIdx.x;
    for (int u = tid; u < NTOK * HD; u += 256) {
        int d = u / NTOK, j = u - d * NTOK;
        vl[j * HD + d] = qkv[(size_t)(2 * C_ + h * HD + d) * TOKS + b * NTOK + j];
    }
    __syncthreads();
    const float* Sp = Sws + (size_t)(b * HEADS_ + h) * (NTOK * NTOK);
    if (tid < NTOK) {
        int i = tid;
        float mx = -1e30f;
        for (int j = 0; j < NTOK; ++j) mx = fmaxf(mx, Sp[i * NTOK + j]);
        float sum = 0.f;
        for (int j = 0; j < NTOK; ++j) { float e = expf(Sp[i * NTOK + j] - mx); P[i * 100 + j] = e; sum += e; }
        float inv = 1.f / sum;
        for (int j = 0; j < NTOK; ++j) P[i * 100 + j] *= inv;
    }
    __syncthreads();
    if (tid < HD) {
        int d = tid;
        float a = 0.f;
        for (int j = 0; j < NTOK; ++j) a += P[K_TOP * 100 + j] * vl[j * HD + d];
        bgrow[d] = a;
        bgres[b * C_ + h * HD + d] = a;
    }
    __syncthreads();
    for (int u = tid; u < K_TOP * HD; u += 256) {
        int d = u / K_TOP, i = u - d * K_TOP;
        float a = 0.f;
        for (int j = 0; j < NTOK; ++j) a += P[i * 100 + j] * vl[j * HD + d];
        diffT[(size_t)(h * HD + d) * N_ + b * K_TOP + i] = f2b(a - bgrow[d]);
    }
}

// depthwise 3x3 SAME, in-place on h1 (bf16; full plane staged before writes)
// Vectorized: 8 outputs/thread, b128 LDS reads, short8 global I/O.
__launch_bounds__(256)
__global__ void k_dwconv(u16* __restrict__ h1, const float* __restrict__ dw_w) {
    int bc = blockIdx.x;
    int c = bc % C_;
    __shared__ __attribute__((aligned(16))) u16 tile[4256];   // 59*72=4248, pad to /8
    int tid = threadIdx.x;
#pragma unroll
    for (int i = tid; i < 532; i += 256)
        *(short8*)(void*)&tile[i * 8] = (short8)0;
    float w[9];
#pragma unroll
    for (int t = 0; t < 9; ++t) w[t] = dw_w[c * 9 + t];
    __syncthreads();
    u16* src = h1 + (size_t)bc * N_;
    for (int i = tid; i < 392; i += 256) {
        int y = i / 7, xg = i - y * 7;
        short8 v = *(const short8*)(const void*)(src + i * 8);
        *(short8*)(void*)&tile[(y + 2) * 72 + xg * 8] = v;
    }
    __syncthreads();
    for (int g = tid; g < 392; g += 256) {
        int y = g / 7, xg = (g - y * 7) * 8;
        float out[8];
#pragma unroll
        for (int t = 0; t < 8; ++t) out[t] = 0.f;
#pragma unroll
        for (int ky = 0; ky < 3; ++ky) {
            const u16* rp = &tile[(y + ky + 1) * 72 + xg];
            short8 mid = *(const short8*)(const void*)rp;
            float r[10];
            r[0] = b2f(rp[-1]);
#pragma unroll
            for (int t = 0; t < 8; ++t) r[t + 1] = b2f((u16)mid[t]);
            r[9] = b2f(rp[8]);
#pragma unroll
            for (int kx = 0; kx < 3; ++kx) {
                float wv = w[ky * 3 + kx];
#pragma unroll
                for (int t = 0; t < 8; ++t) out[t] += wv * r[t + kx];
            }
        }
        short8 o;
#pragma unroll
        for (int t = 0; t < 8; ++t) o[t] = (short)f2b(out[t]);
        *(short8*)(void*)(src + g * 8) = o;
    }
}

// ---------------- launch ----------------

extern "C" void kernel_launch(void* const* d_in, const int* in_sizes, int n_in,
                              void* d_out, int out_size, void* d_ws, size_t ws_size,
                              hipStream_t stream) {
    (void)in_sizes; (void)n_in; (void)out_size; (void)ws_size;
    const float* x      = (const float*)d_in[0];
    const float* qkv_w  = (const float*)d_in[1];
    const float* qkv_b  = (const float*)d_in[2];
    const float* proj_w = (const float*)d_in[3];
    const float* proj_b = (const float*)d_in[4];
    const float* bn_g   = (const float*)d_in[5];
    const float* bn_b   = (const float*)d_in[6];
    const float* fc1_w  = (const float*)d_in[7];
    const float* fc1_b  = (const float*)d_in[8];
    const float* fc2_w  = (const float*)d_in[9];
    const float* fc2_b  = (const float*)d_in[10];
    const float* dw_w   = (const float*)d_in[11];
    const float* dw_b   = (const float*)d_in[12];
    float* out = (float*)d_out;

    // d_out (154 MB f32) doubles as early scratch; only the final GEMM writes it.
    float* qkvF = (float*)d_out;                                         // 14.6 MB
    float* Sws  = (float*)((char*)d_out + (size_t)3 * C_ * TOKS * 4);    // 10.0 MB
    u16*   xb   = (u16*)((char*)d_out + (size_t)32 * 1024 * 1024);       // 77 MB bf16 x

    char* w = (char*)d_ws;
    constexpr size_t o_h1      = 0;                                      // bf16 h1/h2
    constexpr size_t o_scores  = o_h1      + (size_t)B_ * C_ * N_ * 2;   // 77.07 MB
    constexpr size_t o_chsum   = o_scores  + (size_t)B_ * N_ * 4;
    constexpr size_t o_sumsq   = o_chsum   + (size_t)B_ * C_ * 4;
    constexpr size_t o_idx     = o_sumsq   + (size_t)C_ * 4;
    constexpr size_t o_istop   = o_idx     + (size_t)B_ * K_TOP * 4;
    constexpr size_t o_tokens  = o_istop   + (size_t)B_ * N_ * 4;
    constexpr size_t o_ascale  = o_tokens  + (size_t)C_ * TOKS * 2;
    constexpr size_t o_bshift  = o_ascale  + (size_t)C_ * 4;
    constexpr size_t o_w1p     = o_bshift  + (size_t)C_ * 4;
    constexpr size_t o_bias1   = o_w1p     + (size_t)C_ * C_ * 2;
    constexpr size_t o_mw      = o_bias1   + (size_t)C_ * 4;
    constexpr size_t o_biasM   = o_mw      + (size_t)C_ * C_ * 2;
    constexpr size_t o_bias2p  = o_biasM   + (size_t)C_ * 4;
    constexpr size_t o_cbias   = o_bias2p  + (size_t)C_ * 4;
    constexpr size_t o_bgres   = o_cbias   + (size_t)B_ * C_ * 4;
    constexpr size_t o_difft   = o_bgres   + (size_t)B_ * C_ * 4;
    constexpr size_t o_delta2  = o_difft   + (size_t)C_ * N_ * 2;
    constexpr size_t o_wq16    = o_delta2  + (size_t)C_ * N_ * 4;
    constexpr size_t o_pw16    = o_wq16    + (size_t)3 * C_ * C_ * 2;
    constexpr size_t o_spart   = o_pw16    + (size_t)C_ * C_ * 2;        // 2.4 MB

    u16*   h1      = (u16*)(w + o_h1);
    float* scores  = (float*)(w + o_scores);
    float* ch_sum  = (float*)(w + o_chsum);
    float* sumsq   = (float*)(w + o_sumsq);
    int*   idx     = (int*)(w + o_idx);
    int*   istop   = (int*)(w + o_istop);
    u16*   tokensT = (u16*)(w + o_tokens);
    float* a_scale = (float*)(w + o_ascale);
    float* b_shift = (float*)(w + o_bshift);
    u16*   W1p     = (u16*)(w + o_w1p);
    float* bias1   = (float*)(w + o_bias1);
    u16*   Mw      = (u16*)(w + o_mw);
    float* biasM   = (float*)(w + o_biasM);
    float* bias2p  = (float*)(w + o_bias2p);
    float* cbias   = (float*)(w + o_cbias);
    float* bgres   = (float*)(w + o_bgres);
    u16*   diffT   = (u16*)(w + o_difft);
    float* Delta2  = (float*)(w + o_delta2);
    u16*   Wq16    = (u16*)(w + o_wq16);
    u16*   Pw16    = (u16*)(w + o_pw16);
    float* spart   = (float*)(w + o_spart);

    k_zero<<<1, C_, 0, stream>>>(sumsq);
    // fused: one pass over x -> ch_sum, sumsq, score partials, bf16 x copy
    k_xprep<<<dim3(B_, 6), 256, 0, stream>>>(x, ch_sum, sumsq, spart, xb);
    k_scores_fin<<<(B_ * N_) / 256, 256, 0, stream>>>(spart, scores);
    k_topk<<<B_, 1024, 0, stream>>>(scores, idx, istop);
    k_tokens<<<dim3(B_, 6), 256, 0, stream>>>(x, idx, ch_sum, tokensT);
    k_bnfin<<<1, C_, 0, stream>>>(ch_sum, sumsq, bn_g, bn_b, a_scale, b_shift);
    k_bias2p<<<96, 256, 0, stream>>>(fc2_w, fc2_b, dw_b, bias2p);
    k_mw<<<C_, C_, 0, stream>>>(proj_w, fc2_w, Mw);
    k_biasM<<<96, 256, 0, stream>>>(proj_w, proj_b, bias2p, biasM);
    k_w1p<<<(C_ * C_ + 255) / 256, 256, 0, stream>>>(fc1_w, a_scale, W1p);
    k_bias1<<<96, 256, 0, stream>>>(fc1_w, fc1_b, b_shift, bias1);
    k_cvt<<<(3 * C_ * C_ + 255) / 256, 256, 0, stream>>>(qkv_w, Wq16, 3 * C_ * C_);
    k_cvt<<<(C_ * C_ + 255) / 256, 256, 0, stream>>>(proj_w, Pw16, C_ * C_);

    // qkv GEMM (into d_out scratch)
    k_gemm_qkv<<<dim3(9, 50), 256, 0, stream>>>(Wq16, tokensT, qkv_b, qkvF);
    k_attn_scores<<<dim3(B_, HEADS_), 256, 0, stream>>>(qkvF, Sws);
    k_attn_out<<<dim3(B_, HEADS_), 256, 0, stream>>>(qkvF, Sws, diffT, bgres);
    k_cbias<<<dim3(96, B_), 256, 0, stream>>>(proj_w, biasM, bgres, cbias);
    // Delta GEMM: Delta2[o][b*98+i] = proj @ diffT   (B_*K_TOP == N_ == 3136)
    k_gemm2<2><<<dim3(49, 1), 512, 0, stream>>>(Pw16, diffT, 0,
        nullptr, Delta2, nullptr, nullptr, nullptr, nullptr);
    // fc1 GEMM -> h1 (bf16, ws); B = xb (bf16 copy written by k_xprep)
    k_gemm2<1><<<dim3(49, 32), 512, 0, stream>>>(W1p, xb, (long)C_ * N_,
        bias1, nullptr, h1, nullptr, nullptr, nullptr);
    // depthwise conv in-place on h1 -> h2
    k_dwconv<<<B_ * C_, 256, 0, stream>>>(h1, dw_w);
    // final M-GEMM: reads h2 (ws), writes f32 output to d_out
    k_gemm2<3><<<dim3(49, 32), 512, 0, stream>>>(Mw, h1, (long)C_ * N_,
        nullptr, out, nullptr, cbias, istop, Delta2);
}

// Round 5
// 727.660 us; speedup vs baseline: 1.1673x; 1.1673x over previous
//
#include <hip/hip_runtime.h>
#include <hip/hip_bf16.h>
#include <math.h>

typedef unsigned short u16;
typedef short short8 __attribute__((ext_vector_type(8)));
typedef float floatx4 __attribute__((ext_vector_type(4)));

#define B_    32
#define C_    384
#define N_    3136
#define K_TOP 98
#define NTOK  99
#define TOKS  (B_ * NTOK)   // 3168
#define HEADS_ 8
#define HD    48
#define KDIM  384

__device__ __forceinline__ float b2f(u16 u) {
    unsigned int x = ((unsigned int)u) << 16;
    return __builtin_bit_cast(float, x);
}
__device__ __forceinline__ u16 f2b(float f) {
    unsigned int x = __builtin_bit_cast(unsigned int, f);
    unsigned int r = (x + 0x7fffu + ((x >> 16) & 1u)) >> 16;
    return (u16)r;
}
__device__ __forceinline__ u16 tob16(float f) { return f2b(f); }
__device__ __forceinline__ u16 tob16(u16 u) { return u; }

// ---------------- small prep kernels ----------------

__global__ void k_zero(float* sumsq) { sumsq[threadIdx.x] = 0.f; }

__global__ void k_cvt(const float* __restrict__ src, u16* __restrict__ dst, int n) {
    int i = blockIdx.x * 256 + threadIdx.x;
    if (i < n) dst[i] = f2b(src[i]);
}

// scores[b*N+p] = sum_c x^2   (392 blocks; lanes coalesced across p per c-step)
__global__ void k_scores(const float* __restrict__ x, float* __restrict__ scores) {
    int gid = blockIdx.x * 256 + threadIdx.x;   // exactly B_*N_ threads
    int b = gid / N_;
    int p = gid - b * N_;
    const float* xp = x + (size_t)b * C_ * N_ + p;
    float s = 0.f;
#pragma unroll 8
    for (int c = 0; c < C_; ++c) {
        float v = xp[(size_t)c * N_];
        s += v * v;
    }
    scores[gid] = s;
}

// per (b,c): sum_p x -> ch_sum ; atomic sum of x^2 into sumsq[c]
__global__ void k_chsum(const float* __restrict__ x, float* __restrict__ ch_sum,
                        float* __restrict__ sumsq) {
    int bc = blockIdx.x;            // b*C_ + c
    int c = bc % C_;
    const float* xp = x + (size_t)bc * N_;
    float s1 = 0.f, s2 = 0.f;
    for (int p = threadIdx.x; p < N_; p += 256) {
        float v = xp[p];
        s1 += v; s2 += v * v;
    }
#pragma unroll
    for (int off = 32; off; off >>= 1) {
        s1 += __shfl_down(s1, off);
        s2 += __shfl_down(s2, off);
    }
    __shared__ float r1[4], r2[4];
    int wave = threadIdx.x >> 6;
    if ((threadIdx.x & 63) == 0) { r1[wave] = s1; r2[wave] = s2; }
    __syncthreads();
    if (threadIdx.x == 0) {
        float a = r1[0] + r1[1] + r1[2] + r1[3];
        float b2 = r2[0] + r2[1] + r2[2] + r2[3];
        ch_sum[bc] = a;
        atomicAdd(&sumsq[c], b2);
    }
}

// per-batch exact top-98 via 3-pass radix select (ties -> lowest index).
// 1024 threads; single-wave shuffle suffix-scan to find the boundary bin;
// parallel tie collection (serial fallback only if >128 exact ties).
__launch_bounds__(1024)
__global__ void k_topk(const float* __restrict__ scores, int* __restrict__ idx,
                       int* __restrict__ istop) {
    int b = blockIdx.x;
    int tid = threadIdx.x;
    __shared__ unsigned int keys[N_];
    __shared__ int hist[4096];
    __shared__ unsigned int sh_prefix;
    __shared__ int sh_g;
    __shared__ int c1, tc;
    __shared__ int idxbuf[K_TOP];
    __shared__ int tiebuf[128];

    for (int p = tid; p < N_; p += 1024) {
        keys[p] = __builtin_bit_cast(unsigned int, scores[b * N_ + p]);
        istop[b * N_ + p] = 0;
    }

    int Kcur = K_TOP;
    unsigned int prefix = 0;
    int m = 0;
#pragma unroll
    for (int pass = 0; pass < 3; ++pass) {
        const int shift = (pass == 0) ? 20 : (pass == 1 ? 8 : 0);
        const int nbins = (pass == 2) ? 256 : 4096;
        const unsigned int pm = (pass == 0) ? 0u : (pass == 1 ? 0xFFF00000u : 0xFFFFFF00u);
        for (int i = tid; i < nbins; i += 1024) hist[i] = 0;
        __syncthreads();
        for (int p = tid; p < N_; p += 1024) {
            unsigned int u = keys[p];
            if ((u & pm) == prefix) atomicAdd(&hist[(u >> shift) & (nbins - 1)], 1);
        }
        __syncthreads();
        if (tid < 64) {
            int lane = tid;
            int nch = nbins >> 6;           // 64 (passes 0,1) or 4 (pass 2)
            int s = 0;
            for (int j = 0; j < nch; ++j) s += hist[lane * nch + j];
            int suf = s;                    // inclusive suffix sum over lanes >= lane
#pragma unroll
            for (int off = 1; off < 64; off <<= 1) {
                int v = __shfl_down(suf, off);
                if (lane + off < 64) suf += v;
            }
            int above = suf - s;            // sum over lanes > lane
            if (suf >= Kcur && above < Kcur) {   // exactly one lane hits
                int acc = above;
                int bin = (lane + 1) * nch - 1;
                for (;; --bin) {
                    int h = hist[bin];
                    if (acc + h >= Kcur) break;
                    acc += h;
                }
                sh_prefix = prefix | ((unsigned int)bin << shift);
                sh_g = acc;
            }
        }
        __syncthreads();
        prefix = sh_prefix;
        m += sh_g;
        Kcur -= sh_g;
    }

    unsigned int lo = prefix;    // exact K-th largest key
    if (tid == 0) { c1 = 0; tc = 0; }
    __syncthreads();
    for (int p = tid; p < N_; p += 1024) {
        unsigned int u = keys[p];
        if (u > lo) { int pos = atomicAdd(&c1, 1); idxbuf[pos] = p; }
        else if (u == lo) { int pos = atomicAdd(&tc, 1); if (pos < 128) tiebuf[pos] = p; }
    }
    __syncthreads();
    if (tid == 0) {              // ties: the (K-m) lowest indices among keys == lo
        int need = K_TOP - m;
        if (tc <= 128) {
            int cnt = tc;
            for (int r = 0; r < need; ++r) {
                int mi = r;
                for (int q = r + 1; q < cnt; ++q) if (tiebuf[q] < tiebuf[mi]) mi = q;
                int t = tiebuf[mi]; tiebuf[mi] = tiebuf[r]; tiebuf[r] = t;
                idxbuf[m + r] = t;
            }
        } else {                 // degenerate mass-tie fallback (never in practice)
            int picked = 0;
            for (int p = 0; p < N_ && picked < need; ++p)
                if (keys[p] == lo) { idxbuf[m + picked] = p; ++picked; }
        }
    }
    __syncthreads();
    if (tid < K_TOP) {
        int ib = idxbuf[tid];
        idx[b * K_TOP + tid] = ib;
        istop[b * N_ + ib] = tid + 1;
    }
}

// tokensT[c][b*99+j] : gather top tokens + bg token. grid (B_, 6); 4 lanes per c.
__launch_bounds__(256)
__global__ void k_tokens(const float* __restrict__ x, const int* __restrict__ idx,
                         const float* __restrict__ ch_sum, u16* __restrict__ tokensT) {
    int b = blockIdx.x, cg = blockIdx.y;
    __shared__ int il[K_TOP];
    int tid = threadIdx.x;
    if (tid < K_TOP) il[tid] = idx[b * K_TOP + tid];
    __syncthreads();
    int cl = tid >> 2;          // 0..63
    int js = tid & 3;           // 0..3
    int c = cg * 64 + cl;
    const float* xp = x + (size_t)b * C_ * N_ + (size_t)c * N_;
    u16* tp = tokensT + (size_t)c * TOKS + b * NTOK;
    float s = 0.f;
    for (int j = js; j < K_TOP; j += 4) {
        float v = xp[il[j]];
        tp[j] = f2b(v);
        s += v;
    }
    s += __shfl_down(s, 2);
    s += __shfl_down(s, 1);
    if (js == 0) {
        float bg = (ch_sum[b * C_ + c] - s) * (1.0f / (float)(N_ - K_TOP));
        tp[K_TOP] = f2b(bg);
    }
}

__global__ void k_bnfin(const float* ch_sum, const float* sumsq, const float* bn_g,
                        const float* bn_b, float* a_scale, float* b_shift) {
    int c = threadIdx.x;
    float s = 0.f;
    for (int b = 0; b < B_; ++b) s += ch_sum[b * C_ + c];
    float inv_n = 1.0f / (float)(B_ * N_);
    float mu = s * inv_n;
    float var = sumsq[c] * inv_n - mu * mu;
    float a = rsqrtf(var + 1e-5f) * bn_g[c];
    a_scale[c] = a;
    b_shift[c] = bn_b[c] - mu * a;
}

// grid 96: wave per output c; coalesced row reads + shuffle reduce
__global__ void k_bias2p(const float* __restrict__ fc2_w, const float* __restrict__ fc2_b,
                         const float* __restrict__ dw_b, float* __restrict__ bias2p) {
    int c = blockIdx.x * 4 + (threadIdx.x >> 6);
    int l = threadIdx.x & 63;
    float acc = 0.f;
    for (int k = l; k < C_; k += 64) acc += fc2_w[c * C_ + k] * dw_b[k];
#pragma unroll
    for (int off = 32; off; off >>= 1) acc += __shfl_down(acc, off);
    if (l == 0) bias2p[c] = acc + fc2_b[c];
}

__global__ void k_biasM(const float* __restrict__ proj_w, const float* __restrict__ proj_b,
                        const float* __restrict__ bias2p, float* __restrict__ biasM) {
    int o = blockIdx.x * 4 + (threadIdx.x >> 6);
    int l = threadIdx.x & 63;
    float acc = 0.f;
    for (int c = l; c < C_; c += 64) acc += proj_w[o * C_ + c] * bias2p[c];
#pragma unroll
    for (int off = 32; off; off >>= 1) acc += __shfl_down(acc, off);
    if (l == 0) biasM[o] = acc + proj_b[o];
}

__global__ void k_bias1(const float* __restrict__ fc1_w, const float* __restrict__ fc1_b,
                        const float* __restrict__ b_shift, float* __restrict__ bias1) {
    int o = blockIdx.x * 4 + (threadIdx.x >> 6);
    int l = threadIdx.x & 63;
    float acc = 0.f;
    for (int c = l; c < C_; c += 64) acc += fc1_w[o * C_ + c] * b_shift[c];
#pragma unroll
    for (int off = 32; off; off >>= 1) acc += __shfl_down(acc, off);
    if (l == 0) bias1[o] = acc + fc1_b[o];
}

// grid (96, B_): wave per (b,o)
__global__ void k_cbias(const float* __restrict__ proj_w, const float* __restrict__ biasM,
                        const float* __restrict__ bgres, float* __restrict__ cbias) {
    int b = blockIdx.y;
    int o = blockIdx.x * 4 + (threadIdx.x >> 6);
    int l = threadIdx.x & 63;
    float acc = 0.f;
    for (int c = l; c < C_; c += 64) acc += proj_w[o * C_ + c] * bgres[b * C_ + c];
#pragma unroll
    for (int off = 32; off; off >>= 1) acc += __shfl_down(acc, off);
    if (l == 0) cbias[b * C_ + o] = acc + biasM[o];
}

// Mw[o][c] = sum_k proj[o][k]*fc2[k][c]  (f32 -> bf16)
__global__ void k_mw(const float* __restrict__ proj_w, const float* __restrict__ fc2_w,
                     u16* __restrict__ Mw) {
    int o = blockIdx.x, c = threadIdx.x;
    float acc = 0.f;
    for (int k = 0; k < C_; ++k) acc += proj_w[o * C_ + k] * fc2_w[k * C_ + c];
    Mw[o * C_ + c] = f2b(acc);
}

__global__ void k_w1p(const float* fc1_w, const float* a_scale, u16* W1p) {
    int i = blockIdx.x * 256 + threadIdx.x;
    if (i < C_ * C_) {
        int c = i % C_;
        W1p[i] = f2b(fc1_w[i] * a_scale[c]);
    }
}

// ---------------- qkv GEMM (M=1152, NC=3168): bf16 MFMA, f32 out ----------------
__launch_bounds__(256)
__global__ void k_gemm_qkv(const u16* __restrict__ A, const u16* __restrict__ Bsrc,
                           const float* __restrict__ biasB, float* __restrict__ outF) {
    const int ldB = TOKS, NC = TOKS;
    int m0 = blockIdx.x * 128;
    int n0 = blockIdx.y * 64;
    int tid = threadIdx.x;
    int lane = tid & 63;
    int wave = tid >> 6;
    int wm0 = (wave >> 1) * 64;
    int wn0 = (wave & 1) * 32;
    int lm = lane & 15;
    int quad = lane >> 4;

    __shared__ __attribute__((aligned(16))) u16 Al[128 * 32];
    __shared__ __attribute__((aligned(16))) u16 Bl[64 * 32];

    floatx4 acc[4][2];
#pragma unroll
    for (int i = 0; i < 4; ++i)
#pragma unroll
        for (int j = 0; j < 2; ++j)
#pragma unroll
            for (int r = 0; r < 4; ++r) acc[i][j][r] = 0.f;

    int ar = tid >> 2;
    int akc = (tid & 3) * 8;
    int bp = tid & 63;
    int bgi = tid >> 6;
    int bswz = ((bgi ^ ((bp >> 1) & 3)) & 3) * 8;
    int bcol = n0 + bp;
    bool bok = bcol < NC;

    for (int kt = 0; kt < 12; ++kt) {
        int k0 = kt * 32;
        __syncthreads();
#pragma unroll
        for (int i = 0; i < 2; ++i) {
            int r = ar + i * 64;
            short8 v = *(const short8*)(const void*)(A + (size_t)(m0 + r) * KDIM + k0 + akc);
            *(short8*)(void*)&Al[r * 32 + akc] = v;
        }
        {
            const u16* src = Bsrc + (size_t)(k0 + bgi * 8) * ldB + bcol;
            short8 v;
#pragma unroll
            for (int j = 0; j < 8; ++j)
                v[j] = bok ? (short)src[(size_t)j * ldB] : (short)0;
            *(short8*)(void*)&Bl[bp * 32 + bswz] = v;
        }
        __syncthreads();
        short8 af[4], bfv[2];
#pragma unroll
        for (int mt = 0; mt < 4; ++mt)
            af[mt] = *(const short8*)(const void*)&Al[(wm0 + mt * 16 + lm) * 32 + quad * 8];
#pragma unroll
        for (int nt = 0; nt < 2; ++nt) {
            int prow = wn0 + nt * 16 + lm;
            int sw = ((quad ^ ((prow >> 1) & 3)) & 3) * 8;
            bfv[nt] = *(const short8*)(const void*)&Bl[prow * 32 + sw];
        }
#pragma unroll
        for (int mt = 0; mt < 4; ++mt)
#pragma unroll
            for (int nt = 0; nt < 2; ++nt)
                acc[mt][nt] = __builtin_amdgcn_mfma_f32_16x16x32_bf16(af[mt], bfv[nt], acc[mt][nt], 0, 0, 0);
    }

#pragma unroll
    for (int nt = 0; nt < 2; ++nt) {
        int col = n0 + wn0 + nt * 16 + lm;
        if (col >= NC) continue;
#pragma unroll
        for (int mt = 0; mt < 4; ++mt)
#pragma unroll
            for (int r = 0; r < 4; ++r) {
                int o = m0 + wm0 + mt * 16 + quad * 4 + r;
                outF[(size_t)o * TOKS + col] = acc[mt][nt][r] + biasB[o];
            }
    }
}

// ---------------- tall GEMM: OUT[0..383][n0..n0+63] = A(384x384,bf16) * B ----------------
// 8 waves x 48 rows, K chunked 3x128, double-buffered LDS, T14 async-stage split.
// Conflict-free XOR layout: LDS [col][128] u16,
//   u16 offset = (k&64) + (((k>>3 & 7) ^ (col&7))*8) + (k&7)
// Write (short8/thread) and read (b128 fragments) use the same involution.
template<int MODE, typename TB>
__launch_bounds__(512, 4)
__global__ void k_gemm2(const u16* __restrict__ A, const TB* __restrict__ B0, long bStride,
                        const float* __restrict__ biasF,
                        float* __restrict__ outF,
                        u16* __restrict__ outB,
                        const float* __restrict__ cbias, const int* __restrict__ istop,
                        const float* __restrict__ delta2) {
    const int ldB = N_;
    int b = blockIdx.y;
    int n0 = blockIdx.x * 64;
    const TB* Bsrc = B0 + (size_t)b * bStride;
    int tid = threadIdx.x;
    int lane = tid & 63;
    int wave = tid >> 6;          // 0..7
    int wm0 = wave * 48;
    int lm = lane & 15;
    int quad = lane >> 4;

    __shared__ __attribute__((aligned(16))) u16 Bl[2][64 * 128];   // 32 KB

    // staging role: col sc (0..63), k-group kg (0..7); two short8 per chunk
    int sc = tid & 63;
    int kg = tid >> 6;
    int w0 = ((kg ^ (sc & 7)) * 8);     // u16 offset of first window within col row
    const TB* bsp = Bsrc + (size_t)n0 + sc;

    floatx4 acc[3][4];
#pragma unroll
    for (int i = 0; i < 3; ++i)
#pragma unroll
        for (int j = 0; j < 4; ++j)
#pragma unroll
            for (int r = 0; r < 4; ++r) acc[i][j][r] = 0.f;

    TB rv0[8], rv1[8];
    // prologue: load + store chunk 0 into buf 0
    {
        const TB* p0 = bsp + (size_t)(kg * 8) * ldB;
        const TB* p1 = bsp + (size_t)(64 + kg * 8) * ldB;
#pragma unroll
        for (int j = 0; j < 8; ++j) { rv0[j] = p0[(size_t)j * ldB]; rv1[j] = p1[(size_t)j * ldB]; }
        short8 s0, s1;
#pragma unroll
        for (int j = 0; j < 8; ++j) { s0[j] = (short)tob16(rv0[j]); s1[j] = (short)tob16(rv1[j]); }
        *(short8*)(void*)&Bl[0][sc * 128 + w0] = s0;
        *(short8*)(void*)&Bl[0][sc * 128 + 64 + w0] = s1;
    }
    __syncthreads();

    for (int ch = 0; ch < 3; ++ch) {
        int cur = ch & 1;
        if (ch < 2) {   // issue next chunk's loads early (hide HBM under MFMA)
            const TB* p0 = bsp + (size_t)((ch + 1) * 128 + kg * 8) * ldB;
            const TB* p1 = bsp + (size_t)((ch + 1) * 128 + 64 + kg * 8) * ldB;
#pragma unroll
            for (int j = 0; j < 8; ++j) { rv0[j] = p0[(size_t)j * ldB]; rv1[j] = p1[(size_t)j * ldB]; }
        }
#pragma unroll
        for (int kt = 0; kt < 4; ++kt) {
            int k0 = ch * 128 + kt * 32;
            short8 af[3], bfv[4];
#pragma unroll
            for (int mt = 0; mt < 3; ++mt)
                af[mt] = *(const short8*)(const void*)(A + (size_t)(wm0 + mt * 16 + lm) * KDIM + k0 + quad * 8);
#pragma unroll
            for (int nt = 0; nt < 4; ++nt) {
                int pc = nt * 16 + lm;
                int win = kt * 4 + quad;
                bfv[nt] = *(const short8*)(const void*)&Bl[cur][pc * 128 + ((win ^ (pc & 7)) * 8)];
            }
#pragma unroll
            for (int mt = 0; mt < 3; ++mt)
#pragma unroll
                for (int nt = 0; nt < 4; ++nt)
                    acc[mt][nt] = __builtin_amdgcn_mfma_f32_16x16x32_bf16(af[mt], bfv[nt], acc[mt][nt], 0, 0, 0);
        }
        if (ch < 2) {   // write staged regs into the other buffer
            short8 s0, s1;
#pragma unroll
            for (int j = 0; j < 8; ++j) { s0[j] = (short)tob16(rv0[j]); s1[j] = (short)tob16(rv1[j]); }
            *(short8*)(void*)&Bl[cur ^ 1][sc * 128 + w0] = s0;
            *(short8*)(void*)&Bl[cur ^ 1][sc * 128 + 64 + w0] = s1;
            __syncthreads();
        }
    }

#pragma unroll
    for (int nt = 0; nt < 4; ++nt) {
        int ocol = n0 + nt * 16 + lm;
        int tt = 0;
        if (MODE == 3) tt = istop[b * N_ + ocol];
#pragma unroll
        for (int mt = 0; mt < 3; ++mt) {
#pragma unroll
            for (int r = 0; r < 4; ++r) {
                int o = wm0 + mt * 16 + quad * 4 + r;
                float val = acc[mt][nt][r];
                if (MODE == 2) {
                    outF[(size_t)o * N_ + ocol] = val;
                } else if (MODE == 1) {
                    val += biasF[o];
                    float g = 0.5f * val * (1.0f + erff(val * 0.70710678118654752f));
                    outB[(size_t)b * C_ * N_ + (size_t)o * N_ + ocol] = f2b(g);
                } else {
                    val += cbias[b * C_ + o];
                    if (tt) val += delta2[(size_t)o * N_ + b * K_TOP + (tt - 1)];
                    outF[(size_t)b * C_ * N_ + (size_t)o * N_ + ocol] = val;
                }
            }
        }
    }
}

// ---------------- attention (tiny, f32) ----------------

__global__ void k_attn_scores(const float* __restrict__ qkv, float* __restrict__ Sws) {
    int b = blockIdx.x, h = blockIdx.y;
    __shared__ float ql[NTOK * HD], kl[NTOK * HD];
    int tid = threadIdx.x;
    const float scale = 0.14433756729740643f;   // 48^-0.5
    for (int u = tid; u < NTOK * HD; u += 256) {
        int d = u / NTOK, j = u - d * NTOK;
        size_t base = (size_t)(h * HD + d) * TOKS + b * NTOK + j;
        ql[j * HD + d] = qkv[base] * scale;
        kl[j * HD + d] = qkv[base + (size_t)C_ * TOKS];
    }
    __syncthreads();
    float* Sp = Sws + (size_t)(b * HEADS_ + h) * (NTOK * NTOK);
    for (int u = tid; u < NTOK * NTOK; u += 256) {
        int i = u / NTOK, j = u - i * NTOK;
        float s = 0.f;
#pragma unroll 8
        for (int d = 0; d < HD; ++d) s += ql[i * HD + d] * kl[j * HD + d];
        Sp[u] = s;
    }
}

__global__ void k_attn_out(const float* __restrict__ qkv, const float* __restrict__ Sws,
                           u16* __restrict__ diffT, float* __restrict__ bgres) {
    int b = blockIdx.x, h = blockIdx.y;
    __shared__ float vl[NTOK * HD];
    __shared__ float P[NTOK * 100];
    __shared__ float bgrow[HD];
    int tid = threadIdx.x;
    for (int u = tid; u < NTOK * HD; u += 256) {
        int d = u / NTOK, j = u - d * NTOK;
        vl[j * HD + d] = qkv[(size_t)(2 * C_ + h * HD + d) * TOKS + b * NTOK + j];
    }
    __syncthreads();
    const float* Sp = Sws + (size_t)(b * HEADS_ + h) * (NTOK * NTOK);
    if (tid < NTOK) {
        int i = tid;
        float mx = -1e30f;
        for (int j = 0; j < NTOK; ++j) mx = fmaxf(mx, Sp[i * NTOK + j]);
        float sum = 0.f;
        for (int j = 0; j < NTOK; ++j) { float e = expf(Sp[i * NTOK + j] - mx); P[i * 100 + j] = e; sum += e; }
        float inv = 1.f / sum;
        for (int j = 0; j < NTOK; ++j) P[i * 100 + j] *= inv;
    }
    __syncthreads();
    if (tid < HD) {
        int d = tid;
        float a = 0.f;
        for (int j = 0; j < NTOK; ++j) a += P[K_TOP * 100 + j] * vl[j * HD + d];
        bgrow[d] = a;
        bgres[b * C_ + h * HD + d] = a;
    }
    __syncthreads();
    for (int u = tid; u < K_TOP * HD; u += 256) {
        int d = u / K_TOP, i = u - d * K_TOP;
        float a = 0.f;
        for (int j = 0; j < NTOK; ++j) a += P[i * 100 + j] * vl[j * HD + d];
        diffT[(size_t)(h * HD + d) * N_ + b * K_TOP + i] = f2b(a - bgrow[d]);
    }
}

// depthwise 3x3 SAME, in-place on h1 (bf16; full plane staged before writes)
// Vectorized: 8 outputs/thread, b128 LDS reads, short8 global I/O.
__launch_bounds__(256)
__global__ void k_dwconv(u16* __restrict__ h1, const float* __restrict__ dw_w) {
    int bc = blockIdx.x;
    int c = bc % C_;
    __shared__ __attribute__((aligned(16))) u16 tile[4256];   // 59*72=4248, pad to /8
    int tid = threadIdx.x;
#pragma unroll
    for (int i = tid; i < 532; i += 256)
        *(short8*)(void*)&tile[i * 8] = (short8)0;
    float w[9];
#pragma unroll
    for (int t = 0; t < 9; ++t) w[t] = dw_w[c * 9 + t];
    __syncthreads();
    u16* src = h1 + (size_t)bc * N_;
    for (int i = tid; i < 392; i += 256) {
        int y = i / 7, xg = i - y * 7;
        short8 v = *(const short8*)(const void*)(src + i * 8);
        *(short8*)(void*)&tile[(y + 2) * 72 + xg * 8] = v;
    }
    __syncthreads();
    for (int g = tid; g < 392; g += 256) {
        int y = g / 7, xg = (g - y * 7) * 8;
        float out[8];
#pragma unroll
        for (int t = 0; t < 8; ++t) out[t] = 0.f;
#pragma unroll
        for (int ky = 0; ky < 3; ++ky) {
            const u16* rp = &tile[(y + ky + 1) * 72 + xg];
            short8 mid = *(const short8*)(const void*)rp;
            float r[10];
            r[0] = b2f(rp[-1]);
#pragma unroll
            for (int t = 0; t < 8; ++t) r[t + 1] = b2f((u16)mid[t]);
            r[9] = b2f(rp[8]);
#pragma unroll
            for (int kx = 0; kx < 3; ++kx) {
                float wv = w[ky * 3 + kx];
#pragma unroll
                for (int t = 0; t < 8; ++t) out[t] += wv * r[t + kx];
            }
        }
        short8 o;
#pragma unroll
        for (int t = 0; t < 8; ++t) o[t] = (short)f2b(out[t]);
        *(short8*)(void*)(src + g * 8) = o;
    }
}

// ---------------- launch ----------------

extern "C" void kernel_launch(void* const* d_in, const int* in_sizes, int n_in,
                              void* d_out, int out_size, void* d_ws, size_t ws_size,
                              hipStream_t stream) {
    (void)in_sizes; (void)n_in; (void)out_size; (void)ws_size;
    const float* x      = (const float*)d_in[0];
    const float* qkv_w  = (const float*)d_in[1];
    const float* qkv_b  = (const float*)d_in[2];
    const float* proj_w = (const float*)d_in[3];
    const float* proj_b = (const float*)d_in[4];
    const float* bn_g   = (const float*)d_in[5];
    const float* bn_b   = (const float*)d_in[6];
    const float* fc1_w  = (const float*)d_in[7];
    const float* fc1_b  = (const float*)d_in[8];
    const float* fc2_w  = (const float*)d_in[9];
    const float* fc2_b  = (const float*)d_in[10];
    const float* dw_w   = (const float*)d_in[11];
    const float* dw_b   = (const float*)d_in[12];
    float* out = (float*)d_out;

    // d_out (154 MB f32) doubles as early scratch; only the final GEMM writes it.
    float* qkvF = (float*)d_out;                                         // 14.6 MB
    float* Sws  = (float*)((char*)d_out + (size_t)3 * C_ * TOKS * 4);    // 10.0 MB

    char* w = (char*)d_ws;
    constexpr size_t o_h1      = 0;                                      // bf16 h1/h2
    constexpr size_t o_scores  = o_h1      + (size_t)B_ * C_ * N_ * 2;   // 77.07 MB
    constexpr size_t o_chsum   = o_scores  + (size_t)B_ * N_ * 4;
    constexpr size_t o_sumsq   = o_chsum   + (size_t)B_ * C_ * 4;
    constexpr size_t o_idx     = o_sumsq   + (size_t)C_ * 4;
    constexpr size_t o_istop   = o_idx     + (size_t)B_ * K_TOP * 4;
    constexpr size_t o_tokens  = o_istop   + (size_t)B_ * N_ * 4;
    constexpr size_t o_ascale  = o_tokens  + (size_t)C_ * TOKS * 2;
    constexpr size_t o_bshift  = o_ascale  + (size_t)C_ * 4;
    constexpr size_t o_w1p     = o_bshift  + (size_t)C_ * 4;
    constexpr size_t o_bias1   = o_w1p     + (size_t)C_ * C_ * 2;
    constexpr size_t o_mw      = o_bias1   + (size_t)C_ * 4;
    constexpr size_t o_biasM   = o_mw      + (size_t)C_ * C_ * 2;
    constexpr size_t o_bias2p  = o_biasM   + (size_t)C_ * 4;
    constexpr size_t o_cbias   = o_bias2p  + (size_t)C_ * 4;
    constexpr size_t o_bgres   = o_cbias   + (size_t)B_ * C_ * 4;
    constexpr size_t o_difft   = o_bgres   + (size_t)B_ * C_ * 4;
    constexpr size_t o_delta2  = o_difft   + (size_t)C_ * N_ * 2;
    constexpr size_t o_wq16    = o_delta2  + (size_t)C_ * N_ * 4;
    constexpr size_t o_pw16    = o_wq16    + (size_t)3 * C_ * C_ * 2;

    u16*   h1      = (u16*)(w + o_h1);
    float* scores  = (float*)(w + o_scores);
    float* ch_sum  = (float*)(w + o_chsum);
    float* sumsq   = (float*)(w + o_sumsq);
    int*   idx     = (int*)(w + o_idx);
    int*   istop   = (int*)(w + o_istop);
    u16*   tokensT = (u16*)(w + o_tokens);
    float* a_scale = (float*)(w + o_ascale);
    float* b_shift = (float*)(w + o_bshift);
    u16*   W1p     = (u16*)(w + o_w1p);
    float* bias1   = (float*)(w + o_bias1);
    u16*   Mw      = (u16*)(w + o_mw);
    float* biasM   = (float*)(w + o_biasM);
    float* bias2p  = (float*)(w + o_bias2p);
    float* cbias   = (float*)(w + o_cbias);
    float* bgres   = (float*)(w + o_bgres);
    u16*   diffT   = (u16*)(w + o_difft);
    float* Delta2  = (float*)(w + o_delta2);
    u16*   Wq16    = (u16*)(w + o_wq16);
    u16*   Pw16    = (u16*)(w + o_pw16);

    k_zero<<<1, C_, 0, stream>>>(sumsq);
    k_scores<<<(B_ * N_) / 256, 256, 0, stream>>>(x, scores);
    k_chsum<<<B_ * C_, 256, 0, stream>>>(x, ch_sum, sumsq);
    k_topk<<<B_, 1024, 0, stream>>>(scores, idx, istop);
    k_tokens<<<dim3(B_, 6), 256, 0, stream>>>(x, idx, ch_sum, tokensT);
    k_bnfin<<<1, C_, 0, stream>>>(ch_sum, sumsq, bn_g, bn_b, a_scale, b_shift);
    k_bias2p<<<96, 256, 0, stream>>>(fc2_w, fc2_b, dw_b, bias2p);
    k_mw<<<C_, C_, 0, stream>>>(proj_w, fc2_w, Mw);
    k_biasM<<<96, 256, 0, stream>>>(proj_w, proj_b, bias2p, biasM);
    k_w1p<<<(C_ * C_ + 255) / 256, 256, 0, stream>>>(fc1_w, a_scale, W1p);
    k_bias1<<<96, 256, 0, stream>>>(fc1_w, fc1_b, b_shift, bias1);
    k_cvt<<<(3 * C_ * C_ + 255) / 256, 256, 0, stream>>>(qkv_w, Wq16, 3 * C_ * C_);
    k_cvt<<<(C_ * C_ + 255) / 256, 256, 0, stream>>>(proj_w, Pw16, C_ * C_);

    // qkv GEMM (into d_out scratch)
    k_gemm_qkv<<<dim3(9, 50), 256, 0, stream>>>(Wq16, tokensT, qkv_b, qkvF);
    k_attn_scores<<<dim3(B_, HEADS_), 256, 0, stream>>>(qkvF, Sws);
    k_attn_out<<<dim3(B_, HEADS_), 256, 0, stream>>>(qkvF, Sws, diffT, bgres);
    k_cbias<<<dim3(96, B_), 256, 0, stream>>>(proj_w, biasM, bgres, cbias);
    // Delta GEMM: Delta2[o][b*98+i] = proj @ diffT   (B_*K_TOP == N_ == 3136)
    k_gemm2<2, u16><<<dim3(49, 1), 512, 0, stream>>>(Pw16, diffT, 0,
        nullptr, Delta2, nullptr, nullptr, nullptr, nullptr);
    // fc1 GEMM -> h1 (bf16, ws); B = x (f32, converted in staging)
    k_gemm2<1, float><<<dim3(49, 32), 512, 0, stream>>>(W1p, x, (long)C_ * N_,
        bias1, nullptr, h1, nullptr, nullptr, nullptr);
    // depthwise conv in-place on h1 -> h2
    k_dwconv<<<B_ * C_, 256, 0, stream>>>(h1, dw_w);
    // final M-GEMM: reads h2 (ws), writes f32 output to d_out
    k_gemm2<3, u16><<<dim3(49, 32), 512, 0, stream>>>(Mw, h1, (long)C_ * N_,
        nullptr, out, nullptr, cbias, istop, Delta2);
}

// Round 6
// 721.438 us; speedup vs baseline: 1.1773x; 1.0086x over previous
//
#include <hip/hip_runtime.h>
#include <hip/hip_bf16.h>
#include <math.h>

typedef unsigned short u16;
typedef short short8 __attribute__((ext_vector_type(8)));
typedef float floatx4 __attribute__((ext_vector_type(4)));

#define B_    32
#define C_    384
#define N_    3136
#define K_TOP 98
#define NTOK  99
#define TOKS  (B_ * NTOK)   // 3168
#define HEADS_ 8
#define HD    48
#define KDIM  384

__device__ __forceinline__ float b2f(u16 u) {
    unsigned int x = ((unsigned int)u) << 16;
    return __builtin_bit_cast(float, x);
}
__device__ __forceinline__ u16 f2b(float f) {
    unsigned int x = __builtin_bit_cast(unsigned int, f);
    unsigned int r = (x + 0x7fffu + ((x >> 16) & 1u)) >> 16;
    return (u16)r;
}
__device__ __forceinline__ u16 tob16(float f) { return f2b(f); }
__device__ __forceinline__ u16 tob16(u16 u) { return u; }

// ---------------- small prep kernels ----------------

__global__ void k_zero(float* sumsq) { sumsq[threadIdx.x] = 0.f; }

__global__ void k_cvt(const float* __restrict__ src, u16* __restrict__ dst, int n) {
    int i = blockIdx.x * 256 + threadIdx.x;
    if (i < n) dst[i] = f2b(src[i]);
}

// scores[b*N+p] = sum_c x^2   (392 blocks; lanes coalesced across p per c-step)
__global__ void k_scores(const float* __restrict__ x, float* __restrict__ scores) {
    int gid = blockIdx.x * 256 + threadIdx.x;   // exactly B_*N_ threads
    int b = gid / N_;
    int p = gid - b * N_;
    const float* xp = x + (size_t)b * C_ * N_ + p;
    float s = 0.f;
#pragma unroll 8
    for (int c = 0; c < C_; ++c) {
        float v = xp[(size_t)c * N_];
        s += v * v;
    }
    scores[gid] = s;
}

// per (b,c): sum_p x -> ch_sum ; atomic sum of x^2 into sumsq[c]
__global__ void k_chsum(const float* __restrict__ x, float* __restrict__ ch_sum,
                        float* __restrict__ sumsq) {
    int bc = blockIdx.x;            // b*C_ + c
    int c = bc % C_;
    const float* xp = x + (size_t)bc * N_;
    float s1 = 0.f, s2 = 0.f;
    for (int p = threadIdx.x; p < N_; p += 256) {
        float v = xp[p];
        s1 += v; s2 += v * v;
    }
#pragma unroll
    for (int off = 32; off; off >>= 1) {
        s1 += __shfl_down(s1, off);
        s2 += __shfl_down(s2, off);
    }
    __shared__ float r1[4], r2[4];
    int wave = threadIdx.x >> 6;
    if ((threadIdx.x & 63) == 0) { r1[wave] = s1; r2[wave] = s2; }
    __syncthreads();
    if (threadIdx.x == 0) {
        float a = r1[0] + r1[1] + r1[2] + r1[3];
        float b2 = r2[0] + r2[1] + r2[2] + r2[3];
        ch_sum[bc] = a;
        atomicAdd(&sumsq[c], b2);
    }
}

// per-batch exact top-98 via 3-pass radix select (ties -> lowest index).
__launch_bounds__(1024)
__global__ void k_topk(const float* __restrict__ scores, int* __restrict__ idx,
                       int* __restrict__ istop) {
    int b = blockIdx.x;
    int tid = threadIdx.x;
    __shared__ unsigned int keys[N_];
    __shared__ int hist[4096];
    __shared__ unsigned int sh_prefix;
    __shared__ int sh_g;
    __shared__ int c1, tc;
    __shared__ int idxbuf[K_TOP];
    __shared__ int tiebuf[128];

    for (int p = tid; p < N_; p += 1024) {
        keys[p] = __builtin_bit_cast(unsigned int, scores[b * N_ + p]);
        istop[b * N_ + p] = 0;
    }

    int Kcur = K_TOP;
    unsigned int prefix = 0;
    int m = 0;
#pragma unroll
    for (int pass = 0; pass < 3; ++pass) {
        const int shift = (pass == 0) ? 20 : (pass == 1 ? 8 : 0);
        const int nbins = (pass == 2) ? 256 : 4096;
        const unsigned int pm = (pass == 0) ? 0u : (pass == 1 ? 0xFFF00000u : 0xFFFFFF00u);
        for (int i = tid; i < nbins; i += 1024) hist[i] = 0;
        __syncthreads();
        for (int p = tid; p < N_; p += 1024) {
            unsigned int u = keys[p];
            if ((u & pm) == prefix) atomicAdd(&hist[(u >> shift) & (nbins - 1)], 1);
        }
        __syncthreads();
        if (tid < 64) {
            int lane = tid;
            int nch = nbins >> 6;           // 64 (passes 0,1) or 4 (pass 2)
            int s = 0;
            for (int j = 0; j < nch; ++j) s += hist[lane * nch + j];
            int suf = s;                    // inclusive suffix sum over lanes >= lane
#pragma unroll
            for (int off = 1; off < 64; off <<= 1) {
                int v = __shfl_down(suf, off);
                if (lane + off < 64) suf += v;
            }
            int above = suf - s;            // sum over lanes > lane
            if (suf >= Kcur && above < Kcur) {   // exactly one lane hits
                int acc = above;
                int bin = (lane + 1) * nch - 1;
                for (;; --bin) {
                    int h = hist[bin];
                    if (acc + h >= Kcur) break;
                    acc += h;
                }
                sh_prefix = prefix | ((unsigned int)bin << shift);
                sh_g = acc;
            }
        }
        __syncthreads();
        prefix = sh_prefix;
        m += sh_g;
        Kcur -= sh_g;
    }

    unsigned int lo = prefix;    // exact K-th largest key
    if (tid == 0) { c1 = 0; tc = 0; }
    __syncthreads();
    for (int p = tid; p < N_; p += 1024) {
        unsigned int u = keys[p];
        if (u > lo) { int pos = atomicAdd(&c1, 1); idxbuf[pos] = p; }
        else if (u == lo) { int pos = atomicAdd(&tc, 1); if (pos < 128) tiebuf[pos] = p; }
    }
    __syncthreads();
    if (tid == 0) {              // ties: the (K-m) lowest indices among keys == lo
        int need = K_TOP - m;
        if (tc <= 128) {
            int cnt = tc;
            for (int r = 0; r < need; ++r) {
                int mi = r;
                for (int q = r + 1; q < cnt; ++q) if (tiebuf[q] < tiebuf[mi]) mi = q;
                int t = tiebuf[mi]; tiebuf[mi] = tiebuf[r]; tiebuf[r] = t;
                idxbuf[m + r] = t;
            }
        } else {                 // degenerate mass-tie fallback (never in practice)
            int picked = 0;
            for (int p = 0; p < N_ && picked < need; ++p)
                if (keys[p] == lo) { idxbuf[m + picked] = p; ++picked; }
        }
    }
    __syncthreads();
    if (tid < K_TOP) {
        int ib = idxbuf[tid];
        idx[b * K_TOP + tid] = ib;
        istop[b * N_ + ib] = tid + 1;
    }
}

// tokensT[c][b*99+j] : gather top tokens + bg token. grid (B_, 6); 4 lanes per c.
__launch_bounds__(256)
__global__ void k_tokens(const float* __restrict__ x, const int* __restrict__ idx,
                         const float* __restrict__ ch_sum, u16* __restrict__ tokensT) {
    int b = blockIdx.x, cg = blockIdx.y;
    __shared__ int il[K_TOP];
    int tid = threadIdx.x;
    if (tid < K_TOP) il[tid] = idx[b * K_TOP + tid];
    __syncthreads();
    int cl = tid >> 2;          // 0..63
    int js = tid & 3;           // 0..3
    int c = cg * 64 + cl;
    const float* xp = x + (size_t)b * C_ * N_ + (size_t)c * N_;
    u16* tp = tokensT + (size_t)c * TOKS + b * NTOK;
    float s = 0.f;
    for (int j = js; j < K_TOP; j += 4) {
        float v = xp[il[j]];
        tp[j] = f2b(v);
        s += v;
    }
    s += __shfl_down(s, 2);
    s += __shfl_down(s, 1);
    if (js == 0) {
        float bg = (ch_sum[b * C_ + c] - s) * (1.0f / (float)(N_ - K_TOP));
        tp[K_TOP] = f2b(bg);
    }
}

__global__ void k_bnfin(const float* ch_sum, const float* sumsq, const float* bn_g,
                        const float* bn_b, float* a_scale, float* b_shift) {
    int c = threadIdx.x;
    float s = 0.f;
    for (int b = 0; b < B_; ++b) s += ch_sum[b * C_ + c];
    float inv_n = 1.0f / (float)(B_ * N_);
    float mu = s * inv_n;
    float var = sumsq[c] * inv_n - mu * mu;
    float a = rsqrtf(var + 1e-5f) * bn_g[c];
    a_scale[c] = a;
    b_shift[c] = bn_b[c] - mu * a;
}

// grid 96: wave per output c; coalesced row reads + shuffle reduce
__global__ void k_bias2p(const float* __restrict__ fc2_w, const float* __restrict__ fc2_b,
                         const float* __restrict__ dw_b, float* __restrict__ bias2p) {
    int c = blockIdx.x * 4 + (threadIdx.x >> 6);
    int l = threadIdx.x & 63;
    float acc = 0.f;
    for (int k = l; k < C_; k += 64) acc += fc2_w[c * C_ + k] * dw_b[k];
#pragma unroll
    for (int off = 32; off; off >>= 1) acc += __shfl_down(acc, off);
    if (l == 0) bias2p[c] = acc + fc2_b[c];
}

__global__ void k_biasM(const float* __restrict__ proj_w, const float* __restrict__ proj_b,
                        const float* __restrict__ bias2p, float* __restrict__ biasM) {
    int o = blockIdx.x * 4 + (threadIdx.x >> 6);
    int l = threadIdx.x & 63;
    float acc = 0.f;
    for (int c = l; c < C_; c += 64) acc += proj_w[o * C_ + c] * bias2p[c];
#pragma unroll
    for (int off = 32; off; off >>= 1) acc += __shfl_down(acc, off);
    if (l == 0) biasM[o] = acc + proj_b[o];
}

__global__ void k_bias1(const float* __restrict__ fc1_w, const float* __restrict__ fc1_b,
                        const float* __restrict__ b_shift, float* __restrict__ bias1) {
    int o = blockIdx.x * 4 + (threadIdx.x >> 6);
    int l = threadIdx.x & 63;
    float acc = 0.f;
    for (int c = l; c < C_; c += 64) acc += fc1_w[o * C_ + c] * b_shift[c];
#pragma unroll
    for (int off = 32; off; off >>= 1) acc += __shfl_down(acc, off);
    if (l == 0) bias1[o] = acc + fc1_b[o];
}

// grid (96, B_): wave per (b,o)
__global__ void k_cbias(const float* __restrict__ proj_w, const float* __restrict__ biasM,
                        const float* __restrict__ bgres, float* __restrict__ cbias) {
    int b = blockIdx.y;
    int o = blockIdx.x * 4 + (threadIdx.x >> 6);
    int l = threadIdx.x & 63;
    float acc = 0.f;
    for (int c = l; c < C_; c += 64) acc += proj_w[o * C_ + c] * bgres[b * C_ + c];
#pragma unroll
    for (int off = 32; off; off >>= 1) acc += __shfl_down(acc, off);
    if (l == 0) cbias[b * C_ + o] = acc + biasM[o];
}

// Mw[o][c] = sum_k proj[o][k]*fc2[k][c]  (f32 -> bf16)
__global__ void k_mw(const float* __restrict__ proj_w, const float* __restrict__ fc2_w,
                     u16* __restrict__ Mw) {
    int o = blockIdx.x, c = threadIdx.x;
    float acc = 0.f;
    for (int k = 0; k < C_; ++k) acc += proj_w[o * C_ + k] * fc2_w[k * C_ + c];
    Mw[o * C_ + c] = f2b(acc);
}

__global__ void k_w1p(const float* fc1_w, const float* a_scale, u16* W1p) {
    int i = blockIdx.x * 256 + threadIdx.x;
    if (i < C_ * C_) {
        int c = i % C_;
        W1p[i] = f2b(fc1_w[i] * a_scale[c]);
    }
}

// ---------------- qkv GEMM (M=1152, NC=3168): bf16 MFMA, f32 out ----------------
__launch_bounds__(256)
__global__ void k_gemm_qkv(const u16* __restrict__ A, const u16* __restrict__ Bsrc,
                           const float* __restrict__ biasB, float* __restrict__ outF) {
    const int ldB = TOKS, NC = TOKS;
    int m0 = blockIdx.x * 128;
    int n0 = blockIdx.y * 64;
    int tid = threadIdx.x;
    int lane = tid & 63;
    int wave = tid >> 6;
    int wm0 = (wave >> 1) * 64;
    int wn0 = (wave & 1) * 32;
    int lm = lane & 15;
    int quad = lane >> 4;

    __shared__ __attribute__((aligned(16))) u16 Al[128 * 32];
    __shared__ __attribute__((aligned(16))) u16 Bl[64 * 32];

    floatx4 acc[4][2];
#pragma unroll
    for (int i = 0; i < 4; ++i)
#pragma unroll
        for (int j = 0; j < 2; ++j)
#pragma unroll
            for (int r = 0; r < 4; ++r) acc[i][j][r] = 0.f;

    int ar = tid >> 2;
    int akc = (tid & 3) * 8;
    int bp = tid & 63;
    int bgi = tid >> 6;
    int bswz = ((bgi ^ ((bp >> 1) & 3)) & 3) * 8;
    int bcol = n0 + bp;
    bool bok = bcol < NC;

    for (int kt = 0; kt < 12; ++kt) {
        int k0 = kt * 32;
        __syncthreads();
#pragma unroll
        for (int i = 0; i < 2; ++i) {
            int r = ar + i * 64;
            short8 v = *(const short8*)(const void*)(A + (size_t)(m0 + r) * KDIM + k0 + akc);
            *(short8*)(void*)&Al[r * 32 + akc] = v;
        }
        {
            const u16* src = Bsrc + (size_t)(k0 + bgi * 8) * ldB + bcol;
            short8 v;
#pragma unroll
            for (int j = 0; j < 8; ++j)
                v[j] = bok ? (short)src[(size_t)j * ldB] : (short)0;
            *(short8*)(void*)&Bl[bp * 32 + bswz] = v;
        }
        __syncthreads();
        short8 af[4], bfv[2];
#pragma unroll
        for (int mt = 0; mt < 4; ++mt)
            af[mt] = *(const short8*)(const void*)&Al[(wm0 + mt * 16 + lm) * 32 + quad * 8];
#pragma unroll
        for (int nt = 0; nt < 2; ++nt) {
            int prow = wn0 + nt * 16 + lm;
            int sw = ((quad ^ ((prow >> 1) & 3)) & 3) * 8;
            bfv[nt] = *(const short8*)(const void*)&Bl[prow * 32 + sw];
        }
#pragma unroll
        for (int mt = 0; mt < 4; ++mt)
#pragma unroll
            for (int nt = 0; nt < 2; ++nt)
                acc[mt][nt] = __builtin_amdgcn_mfma_f32_16x16x32_bf16(af[mt], bfv[nt], acc[mt][nt], 0, 0, 0);
    }

#pragma unroll
    for (int nt = 0; nt < 2; ++nt) {
        int col = n0 + wn0 + nt * 16 + lm;
        if (col >= NC) continue;
#pragma unroll
        for (int mt = 0; mt < 4; ++mt)
#pragma unroll
            for (int r = 0; r < 4; ++r) {
                int o = m0 + wm0 + mt * 16 + quad * 4 + r;
                outF[(size_t)o * TOKS + col] = acc[mt][nt][r] + biasB[o];
            }
    }
}

// ---------------- tall GEMM: OUT[0..383][n0..n0+63] = A(384x384,bf16) * B ----------------
// Single-shot stage: full K=384 x 64 cols in LDS (48 KB), ONE barrier, then each wave
// computes independently with per-kt A register prefetch. XOR window swizzle
// (win ^ (col&7)) on both write and read. MODE=1 epilogue goes through LDS (reused
// as [384][64] u16) for 128-B-contiguous bf16 stores.
template<int MODE, typename TB>
__launch_bounds__(512, 2)
__global__ void k_gemm2(const u16* __restrict__ A, const TB* __restrict__ B0, long bStride,
                        const float* __restrict__ biasF,
                        float* __restrict__ outF,
                        u16* __restrict__ outB,
                        const float* __restrict__ cbias, const int* __restrict__ istop,
                        const float* __restrict__ delta2) {
    const int ldB = N_;
    int b = blockIdx.y;
    int n0 = blockIdx.x * 64;
    const TB* Bsrc = B0 + (size_t)b * bStride;
    int tid = threadIdx.x;
    int lane = tid & 63;
    int wave = tid >> 6;          // 0..7
    int wm0 = wave * 48;
    int lm = lane & 15;
    int quad = lane >> 4;

    __shared__ __attribute__((aligned(16))) u16 Bl[64 * 384];   // 48 KB [col][k-swz]

    // ---- stage: thread (sc,kg) covers col sc, k in [kg*48, kg*48+48)
    {
        int sc = tid & 63;
        int kg = tid >> 6;
        const TB* bp = Bsrc + (size_t)n0 + sc;
        TB rv[48];
#pragma unroll
        for (int m = 0; m < 6; ++m)
#pragma unroll
            for (int j = 0; j < 8; ++j)
                rv[m * 8 + j] = bp[(size_t)(kg * 48 + m * 8 + j) * ldB];
#pragma unroll
        for (int m = 0; m < 6; ++m) {
            int win = kg * 6 + m;
            short8 s;
#pragma unroll
            for (int j = 0; j < 8; ++j) s[j] = (short)tob16(rv[m * 8 + j]);
            *(short8*)(void*)&Bl[sc * 384 + ((win ^ (sc & 7)) * 8)] = s;
        }
    }

    floatx4 acc[3][4];
#pragma unroll
    for (int i = 0; i < 3; ++i)
#pragma unroll
        for (int j = 0; j < 4; ++j)
#pragma unroll
            for (int r = 0; r < 4; ++r) acc[i][j][r] = 0.f;

    __syncthreads();

    const u16* Ap = A + (size_t)(wm0 + lm) * KDIM + quad * 8;
    short8 af[3], afn[3];
#pragma unroll
    for (int mt = 0; mt < 3; ++mt)
        af[mt] = *(const short8*)(const void*)(Ap + (size_t)(mt * 16) * KDIM);

    for (int kt = 0; kt < 12; ++kt) {
        if (kt < 11) {
#pragma unroll
            for (int mt = 0; mt < 3; ++mt)
                afn[mt] = *(const short8*)(const void*)(Ap + (size_t)(mt * 16) * KDIM + (kt + 1) * 32);
        }
        short8 bfv[4];
#pragma unroll
        for (int nt = 0; nt < 4; ++nt) {
            int pc = nt * 16 + lm;
            int win = kt * 4 + quad;
            bfv[nt] = *(const short8*)(const void*)&Bl[pc * 384 + ((win ^ (pc & 7)) * 8)];
        }
#pragma unroll
        for (int mt = 0; mt < 3; ++mt)
#pragma unroll
            for (int nt = 0; nt < 4; ++nt)
                acc[mt][nt] = __builtin_amdgcn_mfma_f32_16x16x32_bf16(af[mt], bfv[nt], acc[mt][nt], 0, 0, 0);
#pragma unroll
        for (int mt = 0; mt < 3; ++mt) af[mt] = afn[mt];
    }

    if (MODE == 1) {
        // GELU -> LDS tile [o][col] -> coalesced 128-B row stores
        __syncthreads();            // all Bl reads done before overwrite
        u16* hls = Bl;
#pragma unroll
        for (int nt = 0; nt < 4; ++nt)
#pragma unroll
            for (int mt = 0; mt < 3; ++mt)
#pragma unroll
                for (int r = 0; r < 4; ++r) {
                    int o = wm0 + mt * 16 + quad * 4 + r;
                    float val = acc[mt][nt][r] + biasF[o];
                    float g = 0.5f * val * (1.0f + erff(val * 0.70710678118654752f));
                    hls[o * 64 + nt * 16 + lm] = f2b(g);
                }
        __syncthreads();
        int row0 = tid >> 3;        // 0..63
        int cg = (tid & 7) * 8;     // 0..56
        u16* dst = outB + (size_t)b * C_ * N_ + n0;
#pragma unroll
        for (int it = 0; it < 6; ++it) {
            int row = it * 64 + row0;
            short8 v = *(const short8*)(const void*)&hls[row * 64 + cg];
            *(short8*)(void*)(dst + (size_t)row * N_ + cg) = v;
        }
    } else {
#pragma unroll
        for (int nt = 0; nt < 4; ++nt) {
            int ocol = n0 + nt * 16 + lm;
            int tt = 0;
            if (MODE == 3) tt = istop[b * N_ + ocol];
#pragma unroll
            for (int mt = 0; mt < 3; ++mt) {
#pragma unroll
                for (int r = 0; r < 4; ++r) {
                    int o = wm0 + mt * 16 + quad * 4 + r;
                    float val = acc[mt][nt][r];
                    if (MODE == 2) {
                        outF[(size_t)o * N_ + ocol] = val;
                    } else {
                        val += cbias[b * C_ + o];
                        if (tt) val += delta2[(size_t)o * N_ + b * K_TOP + (tt - 1)];
                        outF[(size_t)b * C_ * N_ + (size_t)o * N_ + ocol] = val;
                    }
                }
            }
        }
    }
}

// ---------------- attention (tiny, f32) ----------------

__global__ void k_attn_scores(const float* __restrict__ qkv, float* __restrict__ Sws) {
    int b = blockIdx.x, h = blockIdx.y;
    __shared__ float ql[NTOK * HD], kl[NTOK * HD];
    int tid = threadIdx.x;
    const float scale = 0.14433756729740643f;   // 48^-0.5
    for (int u = tid; u < NTOK * HD; u += 256) {
        int d = u / NTOK, j = u - d * NTOK;
        size_t base = (size_t)(h * HD + d) * TOKS + b * NTOK + j;
        ql[j * HD + d] = qkv[base] * scale;
        kl[j * HD + d] = qkv[base + (size_t)C_ * TOKS];
    }
    __syncthreads();
    float* Sp = Sws + (size_t)(b * HEADS_ + h) * (NTOK * NTOK);
    for (int u = tid; u < NTOK * NTOK; u += 256) {
        int i = u / NTOK, j = u - i * NTOK;
        float s = 0.f;
#pragma unroll 8
        for (int d = 0; d < HD; ++d) s += ql[i * HD + d] * kl[j * HD + d];
        Sp[u] = s;
    }
}

__global__ void k_attn_out(const float* __restrict__ qkv, const float* __restrict__ Sws,
                           u16* __restrict__ diffT, float* __restrict__ bgres) {
    int b = blockIdx.x, h = blockIdx.y;
    __shared__ float vl[NTOK * HD];
    __shared__ float P[NTOK * 100];
    __shared__ float bgrow[HD];
    int tid = threadIdx.x;
    for (int u = tid; u < NTOK * HD; u += 256) {
        int d = u / NTOK, j = u - d * NTOK;
        vl[j * HD + d] = qkv[(size_t)(2 * C_ + h * HD + d) * TOKS + b * NTOK + j];
    }
    __syncthreads();
    const float* Sp = Sws + (size_t)(b * HEADS_ + h) * (NTOK * NTOK);
    if (tid < NTOK) {
        int i = tid;
        float mx = -1e30f;
        for (int j = 0; j < NTOK; ++j) mx = fmaxf(mx, Sp[i * NTOK + j]);
        float sum = 0.f;
        for (int j = 0; j < NTOK; ++j) { float e = expf(Sp[i * NTOK + j] - mx); P[i * 100 + j] = e; sum += e; }
        float inv = 1.f / sum;
        for (int j = 0; j < NTOK; ++j) P[i * 100 + j] *= inv;
    }
    __syncthreads();
    if (tid < HD) {
        int d = tid;
        float a = 0.f;
        for (int j = 0; j < NTOK; ++j) a += P[K_TOP * 100 + j] * vl[j * HD + d];
        bgrow[d] = a;
        bgres[b * C_ + h * HD + d] = a;
    }
    __syncthreads();
    for (int u = tid; u < K_TOP * HD; u += 256) {
        int d = u / K_TOP, i = u - d * K_TOP;
        float a = 0.f;
        for (int j = 0; j < NTOK; ++j) a += P[i * 100 + j] * vl[j * HD + d];
        diffT[(size_t)(h * HD + d) * N_ + b * K_TOP + i] = f2b(a - bgrow[d]);
    }
}

// depthwise 3x3 SAME, in-place on h1 (bf16; full plane staged before writes)
__launch_bounds__(256)
__global__ void k_dwconv(u16* __restrict__ h1, const float* __restrict__ dw_w) {
    int bc = blockIdx.x;
    int c = bc % C_;
    __shared__ __attribute__((aligned(16))) u16 tile[4256];   // 59*72=4248, pad to /8
    int tid = threadIdx.x;
#pragma unroll
    for (int i = tid; i < 532; i += 256)
        *(short8*)(void*)&tile[i * 8] = (short8)0;
    float w[9];
#pragma unroll
    for (int t = 0; t < 9; ++t) w[t] = dw_w[c * 9 + t];
    __syncthreads();
    u16* src = h1 + (size_t)bc * N_;
    for (int i = tid; i < 392; i += 256) {
        int y = i / 7, xg = i - y * 7;
        short8 v = *(const short8*)(const void*)(src + i * 8);
        *(short8*)(void*)&tile[(y + 2) * 72 + xg * 8] = v;
    }
    __syncthreads();
    for (int g = tid; g < 392; g += 256) {
        int y = g / 7, xg = (g - y * 7) * 8;
        float out[8];
#pragma unroll
        for (int t = 0; t < 8; ++t) out[t] = 0.f;
#pragma unroll
        for (int ky = 0; ky < 3; ++ky) {
            const u16* rp = &tile[(y + ky + 1) * 72 + xg];
            short8 mid = *(const short8*)(const void*)rp;
            float r[10];
            r[0] = b2f(rp[-1]);
#pragma unroll
            for (int t = 0; t < 8; ++t) r[t + 1] = b2f((u16)mid[t]);
            r[9] = b2f(rp[8]);
#pragma unroll
            for (int kx = 0; kx < 3; ++kx) {
                float wv = w[ky * 3 + kx];
#pragma unroll
                for (int t = 0; t < 8; ++t) out[t] += wv * r[t + kx];
            }
        }
        short8 o;
#pragma unroll
        for (int t = 0; t < 8; ++t) o[t] = (short)f2b(out[t]);
        *(short8*)(void*)(src + g * 8) = o;
    }
}

// ---------------- launch ----------------

extern "C" void kernel_launch(void* const* d_in, const int* in_sizes, int n_in,
                              void* d_out, int out_size, void* d_ws, size_t ws_size,
                              hipStream_t stream) {
    (void)in_sizes; (void)n_in; (void)out_size; (void)ws_size;
    const float* x      = (const float*)d_in[0];
    const float* qkv_w  = (const float*)d_in[1];
    const float* qkv_b  = (const float*)d_in[2];
    const float* proj_w = (const float*)d_in[3];
    const float* proj_b = (const float*)d_in[4];
    const float* bn_g   = (const float*)d_in[5];
    const float* bn_b   = (const float*)d_in[6];
    const float* fc1_w  = (const float*)d_in[7];
    const float* fc1_b  = (const float*)d_in[8];
    const float* fc2_w  = (const float*)d_in[9];
    const float* fc2_b  = (const float*)d_in[10];
    const float* dw_w   = (const float*)d_in[11];
    const float* dw_b   = (const float*)d_in[12];
    float* out = (float*)d_out;

    // d_out (154 MB f32) doubles as early scratch; only the final GEMM writes it.
    float* qkvF = (float*)d_out;                                         // 14.6 MB
    float* Sws  = (float*)((char*)d_out + (size_t)3 * C_ * TOKS * 4);    // 10.0 MB

    char* w = (char*)d_ws;
    constexpr size_t o_h1      = 0;                                      // bf16 h1/h2
    constexpr size_t o_scores  = o_h1      + (size_t)B_ * C_ * N_ * 2;   // 77.07 MB
    constexpr size_t o_chsum   = o_scores  + (size_t)B_ * N_ * 4;
    constexpr size_t o_sumsq   = o_chsum   + (size_t)B_ * C_ * 4;
    constexpr size_t o_idx     = o_sumsq   + (size_t)C_ * 4;
    constexpr size_t o_istop   = o_idx     + (size_t)B_ * K_TOP * 4;
    constexpr size_t o_tokens  = o_istop   + (size_t)B_ * N_ * 4;
    constexpr size_t o_ascale  = o_tokens  + (size_t)C_ * TOKS * 2;
    constexpr size_t o_bshift  = o_ascale  + (size_t)C_ * 4;
    constexpr size_t o_w1p     = o_bshift  + (size_t)C_ * 4;
    constexpr size_t o_bias1   = o_w1p     + (size_t)C_ * C_ * 2;
    constexpr size_t o_mw      = o_bias1   + (size_t)C_ * 4;
    constexpr size_t o_biasM   = o_mw      + (size_t)C_ * C_ * 2;
    constexpr size_t o_bias2p  = o_biasM   + (size_t)C_ * 4;
    constexpr size_t o_cbias   = o_bias2p  + (size_t)C_ * 4;
    constexpr size_t o_bgres   = o_cbias   + (size_t)B_ * C_ * 4;
    constexpr size_t o_difft   = o_bgres   + (size_t)B_ * C_ * 4;
    constexpr size_t o_delta2  = o_difft   + (size_t)C_ * N_ * 2;
    constexpr size_t o_wq16    = o_delta2  + (size_t)C_ * N_ * 4;
    constexpr size_t o_pw16    = o_wq16    + (size_t)3 * C_ * C_ * 2;

    u16*   h1      = (u16*)(w + o_h1);
    float* scores  = (float*)(w + o_scores);
    float* ch_sum  = (float*)(w + o_chsum);
    float* sumsq   = (float*)(w + o_sumsq);
    int*   idx     = (int*)(w + o_idx);
    int*   istop   = (int*)(w + o_istop);
    u16*   tokensT = (u16*)(w + o_tokens);
    float* a_scale = (float*)(w + o_ascale);
    float* b_shift = (float*)(w + o_bshift);
    u16*   W1p     = (u16*)(w + o_w1p);
    float* bias1   = (float*)(w + o_bias1);
    u16*   Mw      = (u16*)(w + o_mw);
    float* biasM   = (float*)(w + o_biasM);
    float* bias2p  = (float*)(w + o_bias2p);
    float* cbias   = (float*)(w + o_cbias);
    float* bgres   = (float*)(w + o_bgres);
    u16*   diffT   = (u16*)(w + o_difft);
    float* Delta2  = (float*)(w + o_delta2);
    u16*   Wq16    = (u16*)(w + o_wq16);
    u16*   Pw16    = (u16*)(w + o_pw16);

    k_zero<<<1, C_, 0, stream>>>(sumsq);
    k_scores<<<(B_ * N_) / 256, 256, 0, stream>>>(x, scores);
    k_chsum<<<B_ * C_, 256, 0, stream>>>(x, ch_sum, sumsq);
    k_topk<<<B_, 1024, 0, stream>>>(scores, idx, istop);
    k_tokens<<<dim3(B_, 6), 256, 0, stream>>>(x, idx, ch_sum, tokensT);
    k_bnfin<<<1, C_, 0, stream>>>(ch_sum, sumsq, bn_g, bn_b, a_scale, b_shift);
    k_bias2p<<<96, 256, 0, stream>>>(fc2_w, fc2_b, dw_b, bias2p);
    k_mw<<<C_, C_, 0, stream>>>(proj_w, fc2_w, Mw);
    k_biasM<<<96, 256, 0, stream>>>(proj_w, proj_b, bias2p, biasM);
    k_w1p<<<(C_ * C_ + 255) / 256, 256, 0, stream>>>(fc1_w, a_scale, W1p);
    k_bias1<<<96, 256, 0, stream>>>(fc1_w, fc1_b, b_shift, bias1);
    k_cvt<<<(3 * C_ * C_ + 255) / 256, 256, 0, stream>>>(qkv_w, Wq16, 3 * C_ * C_);
    k_cvt<<<(C_ * C_ + 255) / 256, 256, 0, stream>>>(proj_w, Pw16, C_ * C_);

    // qkv GEMM (into d_out scratch)
    k_gemm_qkv<<<dim3(9, 50), 256, 0, stream>>>(Wq16, tokensT, qkv_b, qkvF);
    k_attn_scores<<<dim3(B_, HEADS_), 256, 0, stream>>>(qkvF, Sws);
    k_attn_out<<<dim3(B_, HEADS_), 256, 0, stream>>>(qkvF, Sws, diffT, bgres);
    k_cbias<<<dim3(96, B_), 256, 0, stream>>>(proj_w, biasM, bgres, cbias);
    // Delta GEMM: Delta2[o][b*98+i] = proj @ diffT   (B_*K_TOP == N_ == 3136)
    k_gemm2<2, u16><<<dim3(49, 1), 512, 0, stream>>>(Pw16, diffT, 0,
        nullptr, Delta2, nullptr, nullptr, nullptr, nullptr);
    // fc1 GEMM -> h1 (bf16, ws); B = x (f32, converted in staging)
    k_gemm2<1, float><<<dim3(49, 32), 512, 0, stream>>>(W1p, x, (long)C_ * N_,
        bias1, nullptr, h1, nullptr, nullptr, nullptr);
    // depthwise conv in-place on h1 -> h2
    k_dwconv<<<B_ * C_, 256, 0, stream>>>(h1, dw_w);
    // final M-GEMM: reads h2 (ws), writes f32 output to d_out
    k_gemm2<3, u16><<<dim3(49, 32), 512, 0, stream>>>(Mw, h1, (long)C_ * N_,
        nullptr, out, nullptr, cbias, istop, Delta2);
}